// Round 12
// baseline (257.417 us; speedup 1.0000x reference)
//
#include <hip/hip_runtime.h>
#include <hip/hip_bf16.h>

// Segment counts per scale: ps=2:(128,128,16) ps=4:(64,64,8) ps=6:(43,43,6) ps=8:(32,32,4), B=2
#define SEG1 524288
#define SEG2 589824
#define SEG3 612012
#define SEGT 620204

// k2 block mapping: blocks per scale = ceil(segCount/64) = {8192, 1024, 347, 128}
#define K2B0 8192
#define K2B1 9216
#define K2B2 9563
#define K2BT 9691

#define PYRB12 10968

// ws layout (BYTES):
//   red_bf16   @ 0           : 32,000,000 B
//   sums_bf16  @ 32,000,000  : 79,386,112 B (SEGT*64 bf16 packed)
//   cnt        @ 111,386,112 : 2,480,816 B
//   att_bf16   @ 113,866,928 : 39,693,056 B (end 153,559,984)
//   wq (pre-swizzled bf16 weights) @ 153,560,064 : 63,488 B
#define SUMS_OFF 32000000ull
#define CNT_OFF  111386112ull
#define ATT_OFF  113866928ull
#define WQ_OFF   153560064ull
// wq sections: k1Bw 0 (8192) | k2Bs 8192 (16384, 4096/j) | wz 24576 (2048)
//   | watt 26624 (8192) | wot 34816 (4096) | wl1 38912 (16384) | wl2 55296 (8192)

typedef __attribute__((ext_vector_type(8))) __bf16 bf16x8;
typedef __attribute__((ext_vector_type(4))) float  f32x4;

__device__ __forceinline__ float bf2f(unsigned short u) {
    union { unsigned int i; float f; } v; v.i = ((unsigned int)u) << 16; return v.f;
}
__device__ __forceinline__ unsigned short f2bf(float f) {
    union { float f; unsigned int i; } v; v.f = f;
    unsigned int r = v.i + 0x7FFF + ((v.i >> 16) & 1);
    return (unsigned short)(r >> 16);
}
__device__ __forceinline__ void atom_pk_bf16(unsigned int* addr, unsigned int pk) {
    asm volatile("global_atomic_pk_add_bf16 %0, %1, off" :: "v"(addr), "v"(pk) : "memory");
}

__device__ __forceinline__ int seg0_of(int b, int cx, int cy, int cz) {
    return ((b*128 + (cx>>1))*128 + (cy>>1))*16 + (cz>>1);
}
__device__ __forceinline__ void seg4(int b, int cx, int cy, int cz, int* s) {
    s[0] =        ((b*128 + (cx>>1))*128 + (cy>>1))*16 + (cz>>1);
    s[1] = SEG1 + ((b*64  + (cx>>2))*64  + (cy>>2))*8  + (cz>>2);
    s[2] = SEG2 + ((b*43  + (cx/6 ))*43  + (cy/6 ))*6  + (cz/6 );
    s[3] = SEG3 + ((b*32  + (cx>>3))*32  + (cy>>3))*4  + (cz>>3);
}

// k0: convert + pre-swizzle all weights into wq.
__global__ __launch_bounds__(256) void k0_wprep(
    const float* __restrict__ W_red, const float* __restrict__ W_pool,
    const float* __restrict__ W_z, const float* __restrict__ W_att,
    const float* __restrict__ W_out, const float* __restrict__ W_l1,
    const float* __restrict__ W_l2, char* __restrict__ wq)
{
    int g = blockIdx.x*256 + threadIdx.x;
    if (g < 4096) {
        int idx = g; int k = idx>>6, c = idx&63;
        int byte = (((c<<7)+(k<<1)) ^ ((c&7)<<4));
        *(unsigned short*)(wq + byte) = f2bf(W_red[idx]);
    } else if (g < 12288) {
        int idx = g - 4096; int j = idx>>11, r2 = idx&2047, k = r2>>5, c = r2&31;
        int byte = j*4096 + (((c<<7)+(k<<1)) ^ ((c&7)<<4));
        *(unsigned short*)(wq + 8192 + byte) = f2bf(W_pool[idx]);
    } else if (g < 13312) {
        int idx = g - 12288; int k = idx>>5, c = idx&31;
        *(unsigned short*)(wq + 24576 + ((k>>3)*32+c)*16 + (k&7)*2) = f2bf(W_z[idx]);
    } else if (g < 17408) {
        int idx = g - 13312; int j = idx>>10, rem = idx&1023, k = rem>>5, c = rem&31;
        *(unsigned short*)(wq + 26624 + j*2048 + ((k>>3)*32+c)*16 + (k&7)*2) = f2bf(W_att[idx]);
    } else if (g < 19456) {
        int idx = g - 17408; int k = idx>>6, c = idx&63;
        *(unsigned short*)(wq + 34816 + ((k>>3)*64+c)*16 + (k&7)*2) = f2bf(W_out[idx]);
    } else if (g < 27648) {
        int idx = g - 19456; int k = idx>>6, c = idx&63;
        int byte = (((c<<8)+(k<<1)) ^ ((c&7)<<4));
        *(unsigned short*)(wq + 38912 + byte) = f2bf(W_l1[idx]);
    } else if (g < 31744) {
        int idx = g - 27648; int k = idx>>6, c = idx&63;
        int byte = (((c<<7)+(k<<1)) ^ ((c&7)<<4));
        *(unsigned short*)(wq + 55296 + byte) = f2bf(W_l2[idx]);
    }
}

// k1 via MFMA: red = relu(x@W_red+b) bf16; pk-bf16 atomic scatter to scale-0 only.
__global__ __launch_bounds__(256) void k1_mfma(
    const float* __restrict__ x, const int* __restrict__ coords,
    const char* __restrict__ wq, const float* __restrict__ b_red,
    unsigned int* __restrict__ red32, unsigned int* __restrict__ sums_pk,
    float* __restrict__ cnt, int n)
{
    __shared__ uint4 Ax4[512];
    __shared__ uint4 Bw4[512];
    __shared__ uint4 Rt4[512];
    __shared__ int segl[64];
    char* Ax = (char*)Ax4; char* Bw = (char*)Bw4; char* Rt = (char*)Rt4;

    int t = threadIdx.x;
    int i0 = blockIdx.x * 64;

    if (t < 64) {
        int r = i0 + t;
        if (r < n) {
            int4 cv = *(const int4*)&coords[(size_t)r*4];
            int s0 = seg0_of(cv.x, cv.y, cv.z, cv.w);
            segl[t] = s0;
            unsafeAtomicAdd(&cnt[s0], 1.f);
        } else segl[t] = -1;
    }
    {
        const uint4* src = (const uint4*)wq;
        for (int idx = t; idx < 512; idx += 256) Bw4[idx] = src[idx];
    }
    #pragma unroll
    for (int i2 = 0; i2 < 2; ++i2) {
        int idx = i2*256 + t;
        int row = idx >> 3, kc = idx & 7;
        int r = i0 + row;
        unsigned short u[8];
        if (r < n) {
            float4 v0 = *(const float4*)&x[(size_t)r*64 + kc*8];
            float4 v1 = *(const float4*)&x[(size_t)r*64 + kc*8 + 4];
            u[0]=f2bf(v0.x); u[1]=f2bf(v0.y); u[2]=f2bf(v0.z); u[3]=f2bf(v0.w);
            u[4]=f2bf(v1.x); u[5]=f2bf(v1.y); u[6]=f2bf(v1.z); u[7]=f2bf(v1.w);
        } else {
            #pragma unroll
            for (int q = 0; q < 8; ++q) u[q] = 0;
        }
        int byte = ((row << 7) + (kc << 4)) ^ ((row & 7) << 4);
        *(uint4*)(Ax + byte) = *(const uint4*)u;
    }
    __syncthreads();

    int lane = t & 63, wv = t >> 6;
    int hi = lane >> 4, lo = lane & 15;
    int arow = wv*16 + lo;

    f32x4 acc[4];
    #pragma unroll
    for (int nt = 0; nt < 4; ++nt) acc[nt] = (f32x4){0.f,0.f,0.f,0.f};
    #pragma unroll
    for (int kk = 0; kk < 2; ++kk) {
        int abyte = ((arow << 7) + ((kk*4 + hi) << 4)) ^ ((arow & 7) << 4);
        bf16x8 af = *(const bf16x8*)(Ax + abyte);
        #pragma unroll
        for (int nt = 0; nt < 4; ++nt) {
            int brow = nt*16 + lo;
            int bbyte = ((brow << 7) + ((kk*4 + hi) << 4)) ^ ((brow & 7) << 4);
            bf16x8 bf = *(const bf16x8*)(Bw + bbyte);
            acc[nt] = __builtin_amdgcn_mfma_f32_16x16x32_bf16(af, bf, acc[nt], 0, 0, 0);
        }
    }
    #pragma unroll
    for (int nt = 0; nt < 4; ++nt) {
        int col = nt*16 + lo;
        float bb = b_red[col];
        #pragma unroll
        for (int r = 0; r < 4; ++r) {
            int row = wv*16 + hi*4 + r;
            int byte = ((row << 7) + (col << 1)) ^ ((row & 7) << 4);
            *(unsigned short*)(Rt + byte) = f2bf(fmaxf(acc[nt][r] + bb, 0.f));
        }
    }
    __syncthreads();

    #pragma unroll
    for (int i2 = 0; i2 < 2; ++i2) {
        int idx = i2*256 + t;
        int row = idx >> 3, ck = idx & 7;
        int r = i0 + row;
        if (r < n) {
            int byte = ((row << 7) + (ck << 4)) ^ ((row & 7) << 4);
            *(uint4*)&red32[(size_t)r*32 + ck*4] = *(const uint4*)(Rt + byte);
        }
    }
    {
        int half = t >> 5, c = t & 31;
        #pragma unroll
        for (int i2 = 0; i2 < 8; ++i2) {
            int p = i2*8 + half;
            int s0_ = segl[p];
            if (s0_ >= 0) {
                int byte = ((p << 7) + (c << 2)) ^ ((p & 7) << 4);
                unsigned int pk = *(const unsigned int*)(Rt + byte);
                atom_pk_bf16(&sums_pk[(size_t)s0_*32 + c], pk);
            }
        }
    }
    asm volatile("s_waitcnt vmcnt(0)" ::: "memory");
}

// k_pyramid: scales 1+2 from scale-0; skip empty children (cnt==0 rows are exact zeros).
__global__ __launch_bounds__(256) void k_pyramid(
    unsigned int* __restrict__ sums_pk, float* __restrict__ cnt)
{
    int t = threadIdx.x;
    int lane = t & 31;
    int cg = blockIdx.x * 8 + (t >> 5);

    float a0 = 0.f, a1 = 0.f, ca = 0.f;
    int outSeg = -1;

    if (cg < 65536) {                       // scale 1 (ps=4): 8 children
        int r1 = cg;
        int qz = r1 & 7, qy = (r1 >> 3) & 63, qx = (r1 >> 9) & 63, b = r1 >> 15;
        #pragma unroll
        for (int d = 0; d < 8; ++d) {
            int x2 = 2*qx + (d>>2), y2 = 2*qy + ((d>>1)&1), z2 = 2*qz + (d&1);
            int child = ((b*128 + x2)*128 + y2)*16 + z2;
            float cc = cnt[child];
            if (cc > 0.f) {
                unsigned int v = sums_pk[(size_t)child*32 + lane];
                a0 += bf2f((unsigned short)(v & 0xffff));
                a1 += bf2f((unsigned short)(v >> 16));
                ca += cc;
            }
        }
        outSeg = SEG1 + r1;
    } else {                                // scale 2 (ps=6): <=27 children
        int r2 = cg - 65536;
        if (r2 < 22188) {
            int z6 = r2 % 6; int tmp = r2 / 6;
            int y6 = tmp % 43; tmp /= 43;
            int x6 = tmp % 43; int b = tmp / 43;
            for (int dx = 0; dx < 3; ++dx) {
                int x2 = 3*x6 + dx; if (x2 >= 128) break;
                for (int dy = 0; dy < 3; ++dy) {
                    int y2 = 3*y6 + dy; if (y2 >= 128) break;
                    for (int dz = 0; dz < 3; ++dz) {
                        int z2 = 3*z6 + dz; if (z2 >= 16) break;
                        int child = ((b*128 + x2)*128 + y2)*16 + z2;
                        float cc = cnt[child];
                        if (cc > 0.f) {
                            unsigned int v = sums_pk[(size_t)child*32 + lane];
                            a0 += bf2f((unsigned short)(v & 0xffff));
                            a1 += bf2f((unsigned short)(v >> 16));
                            ca += cc;
                        }
                    }
                }
            }
            outSeg = SEG2 + r2;
        }
    }

    if (outSeg >= 0) {
        unsigned int pk = (unsigned int)f2bf(a0) | ((unsigned int)f2bf(a1) << 16);
        sums_pk[(size_t)outSeg*32 + lane] = pk;
        if (lane == 0) cnt[outSeg] = ca;
    }
}

// k_pyr3: scale 3 (ps=8) from scale-1 children (exact 2x2x2 nesting).
__global__ __launch_bounds__(256) void k_pyr3(
    unsigned int* __restrict__ sums_pk, float* __restrict__ cnt)
{
    int t = threadIdx.x;
    int lane = t & 31;
    int r3 = blockIdx.x * 8 + (t >> 5);
    int z8 = r3 & 3, y8 = (r3 >> 2) & 31, x8 = (r3 >> 7) & 31, b = r3 >> 12;
    float a0 = 0.f, a1 = 0.f, ca = 0.f;
    #pragma unroll
    for (int d = 0; d < 8; ++d) {
        int qx = 2*x8 + (d>>2), qy = 2*y8 + ((d>>1)&1), qz = 2*z8 + (d&1);
        int child = SEG1 + ((b*64 + qx)*64 + qy)*8 + qz;
        unsigned int v = sums_pk[(size_t)child*32 + lane];
        a0 += bf2f((unsigned short)(v & 0xffff));
        a1 += bf2f((unsigned short)(v >> 16));
        if (lane == 0) ca += cnt[child];
    }
    unsigned int pk = (unsigned int)f2bf(a0) | ((unsigned int)f2bf(a1) << 16);
    sums_pk[(size_t)(SEG3 + r3)*32 + lane] = pk;
    if (lane == 0) cnt[SEG3 + r3] = ca;
}

// k2 via MFMA with empty-segment skip (load & store predicated on cnt>0).
__global__ __launch_bounds__(256) void k2_mfma(
    const unsigned int* __restrict__ sums_pk, const float* __restrict__ cnt,
    const char* __restrict__ wq, const float* __restrict__ b_pool,
    unsigned short* __restrict__ att)
{
    __shared__ uint4 As4[512];
    __shared__ uint4 Bs4[256];
    char* As = (char*)As4; char* Bs = (char*)Bs4;

    int t = threadIdx.x;
    int bid = blockIdx.x;
    int j, rel;
    if (bid < K2B0)      { j = 0; rel = bid; }
    else if (bid < K2B1) { j = 1; rel = bid - K2B0; }
    else if (bid < K2B2) { j = 2; rel = bid - K2B1; }
    else                 { j = 3; rel = bid - K2B2; }
    const int segStartT[4] = {0, SEG1, SEG2, SEG3};
    const int segEndT[4]   = {SEG1, SEG2, SEG3, SEGT};
    int s0 = segStartT[j] + rel * 64;
    int sEnd = segEndT[j];

    {
        const uint4* src = (const uint4*)(wq + 8192 + j*4096);
        for (int idx = t; idx < 256; idx += 256) Bs4[idx] = src[idx];
    }
    #pragma unroll
    for (int i = 0; i < 4; ++i) {
        int idx = i*256 + t;
        int p = idx >> 4, c4 = idx & 15;
        int s = s0 + p;
        unsigned int lo = 0, hi2 = 0; float cv = 0.f;
        if (s < sEnd) cv = cnt[s];
        if (cv > 0.f) {
            uint2 v = *(const uint2*)&sums_pk[(size_t)s*32 + c4*2];
            lo = v.x; hi2 = v.y;
        }
        float inv = (cv > 0.f) ? 1.f / cv : 0.f;
        unsigned short u[4] = { f2bf(bf2f((unsigned short)(lo & 0xffff))*inv),
                                f2bf(bf2f((unsigned short)(lo >> 16))*inv),
                                f2bf(bf2f((unsigned short)(hi2 & 0xffff))*inv),
                                f2bf(bf2f((unsigned short)(hi2 >> 16))*inv) };
        int byte = ((p << 7) + (c4 << 3)) ^ ((p & 7) << 4);
        *(uint2*)(As + byte) = *(const uint2*)u;
    }
    __syncthreads();

    int lane = t & 63, wv = t >> 6;
    int hi = lane >> 4, lo = lane & 15;
    int arow = wv*16 + lo;

    f32x4 acc[2];
    acc[0] = (f32x4){0.f,0.f,0.f,0.f};
    acc[1] = (f32x4){0.f,0.f,0.f,0.f};
    #pragma unroll
    for (int kk = 0; kk < 2; ++kk) {
        int abyte = ((arow << 7) + ((kk*4 + hi) << 4)) ^ ((arow & 7) << 4);
        bf16x8 af = *(const bf16x8*)(As + abyte);
        #pragma unroll
        for (int nt = 0; nt < 2; ++nt) {
            int brow = nt*16 + lo;
            int bbyte = ((brow << 7) + ((kk*4 + hi) << 4)) ^ ((brow & 7) << 4);
            bf16x8 bf = *(const bf16x8*)(Bs + bbyte);
            acc[nt] = __builtin_amdgcn_mfma_f32_16x16x32_bf16(af, bf, acc[nt], 0, 0, 0);
        }
    }
    #pragma unroll
    for (int nt = 0; nt < 2; ++nt) {
        int col = nt*16 + lo;
        float bp = b_pool[j*32 + col];
        #pragma unroll
        for (int r = 0; r < 4; ++r) {
            int s = s0 + wv*16 + hi*4 + r;
            if (s < sEnd && cnt[s] > 0.f)
                att[(size_t)s*32 + col] = f2bf(fmaxf(acc[nt][r] + bp, 0.f));
        }
    }
}

// k3 fused: per out-row block. Phase A (k3a math) computes sfeat for rows
// rl[p]=cinv[i0+p], writing straight into the ofs LDS tile; phase B (k3b math)
// computes out = relu([red|sfeat]@W_l1)@W_l2 + b_l2 and stores out[i0+p].
// LDS arena 56576 B with phase aliasing: sf->wl1, wz/watt->wl2, AsWs+Fz->hs.
#define SF_O   0
#define WZ_O   16384
#define WATT_O 18432
#define WL2_O  16384
#define WOT_O  26624
#define ASWS_O 30720
#define FZ_O   34816
#define HS_O   30720
#define OFS_O  38912
#define SEGL_O 55296
#define RL_O   56320
__global__ __launch_bounds__(256) void k3_fused(
    const int* __restrict__ coords, const int* __restrict__ cinv,
    const unsigned short* __restrict__ att, const unsigned short* __restrict__ red,
    const char* __restrict__ wq, const float* __restrict__ b_att,
    const float* __restrict__ b_l2, float* __restrict__ out, int n)
{
    __shared__ uint4 L4[3536];   // 56576 B
    char* L = (char*)L4;
    int* segl = (int*)(L + SEGL_O);   // [64][4]
    int* rl   = (int*)(L + RL_O);     // [64]

    int t = threadIdx.x;
    int i0 = blockIdx.x * 64;

    if (t < 64) {
        int i = i0 + t;
        int r = cinv[(i < n) ? i : (n - 1)];
        rl[t] = r;
        int sg[4]; seg4(coords[r*4], coords[r*4+1], coords[r*4+2], coords[r*4+3], sg);
        segl[t*4+0]=sg[0]; segl[t*4+1]=sg[1]; segl[t*4+2]=sg[2]; segl[t*4+3]=sg[3];
    }
    {   // stage wz+watt+wot (896 uint4) into region2
        const uint4* src = (const uint4*)(wq + 24576);
        uint4* dst = (uint4*)(L + WZ_O);
        for (int idx = t; idx < 896; idx += 256) dst[idx] = src[idx];
    }
    __syncthreads();

    // gather att + fused shfl-ssum -> AsWs; gather red -> ofs cols 0..63
    #pragma unroll
    for (int i = 0; i < 4; ++i) {
        int idx = i*256 + t;
        int p = idx >> 4, j = (idx >> 2) & 3, ck = idx & 3;
        int s = segl[p*4+j];
        uint4 v = *(const uint4*)(att + (size_t)s*32 + ck*8);
        int off = (j*64 + ck*16) ^ (((p>>2)&3) << 4);
        *(uint4*)(L + SF_O + p*256 + off) = v;
        unsigned int w_[4] = {v.x, v.y, v.z, v.w};
        float f[8];
        #pragma unroll
        for (int q = 0; q < 4; ++q) {
            f[2*q]   = bf2f((unsigned short)(w_[q] & 0xffff));
            f[2*q+1] = bf2f((unsigned short)(w_[q] >> 16));
        }
        #pragma unroll
        for (int q = 0; q < 8; ++q) {
            f[q] += __shfl_xor(f[q], 4);
            f[q] += __shfl_xor(f[q], 8);
        }
        if (j == 0) {
            unsigned short u8[8];
            #pragma unroll
            for (int q = 0; q < 8; ++q) u8[q] = f2bf(f[q]);
            *(uint4*)(L + ASWS_O + (ck*64 + p)*16) = *(const uint4*)u8;
        }
    }
    #pragma unroll
    for (int i = 0; i < 2; ++i) {
        int idx = i*256 + t;
        int p = idx >> 3, c = idx & 7;
        int r = rl[p];
        uint4 v = *(const uint4*)(red + (size_t)r*64 + c*8);
        int byte = ((p << 8) + (c << 4)) ^ ((p & 7) << 4);
        *(uint4*)(L + OFS_O + byte) = v;
    }
    __syncthreads();

    int lane = t & 63, wv = t >> 6;
    int hi = lane >> 4, lo = lane & 15;
    int arow = wv*16 + lo;

    // fz = relu(ssum @ Wz), K=32
    {
        bf16x8 af = *(const bf16x8*)(L + ASWS_O + (hi*64 + arow)*16);
        f32x4 d0 = (f32x4){0.f,0.f,0.f,0.f}, d1 = (f32x4){0.f,0.f,0.f,0.f};
        bf16x8 b0 = *(const bf16x8*)(L + WZ_O + (hi*32 + lo)*16);
        bf16x8 b1 = *(const bf16x8*)(L + WZ_O + (hi*32 + 16 + lo)*16);
        d0 = __builtin_amdgcn_mfma_f32_16x16x32_bf16(af, b0, d0, 0,0,0);
        d1 = __builtin_amdgcn_mfma_f32_16x16x32_bf16(af, b1, d1, 0,0,0);
        #pragma unroll
        for (int r = 0; r < 4; ++r) {
            int row = wv*16 + hi*4 + r;
            int c0 = lo, c1 = 16 + lo;
            *(unsigned short*)(L + FZ_O + ((c0>>3)*64 + row)*16 + (c0&7)*2) = f2bf(fmaxf(d0[r], 0.f));
            *(unsigned short*)(L + FZ_O + ((c1>>3)*64 + row)*16 + (c1&7)*2) = f2bf(fmaxf(d1[r], 0.f));
        }
    }
    __syncthreads();
    // wsum = sum_j sf_j * sigmoid(fz @ Watt_j + b_att_j) -> AsWs
    {
        float wacc[2][4] = {{0.f,0.f,0.f,0.f},{0.f,0.f,0.f,0.f}};
        bf16x8 af = *(const bf16x8*)(L + FZ_O + (hi*64 + arow)*16);
        #pragma unroll
        for (int j = 0; j < 4; ++j) {
            f32x4 d0 = (f32x4){0.f,0.f,0.f,0.f}, d1 = (f32x4){0.f,0.f,0.f,0.f};
            bf16x8 b0 = *(const bf16x8*)(L + WATT_O + j*2048 + (hi*32 + lo)*16);
            bf16x8 b1 = *(const bf16x8*)(L + WATT_O + j*2048 + (hi*32 + 16 + lo)*16);
            d0 = __builtin_amdgcn_mfma_f32_16x16x32_bf16(af, b0, d0, 0,0,0);
            d1 = __builtin_amdgcn_mfma_f32_16x16x32_bf16(af, b1, d1, 0,0,0);
            float ba0 = b_att[j*32 + lo], ba1 = b_att[j*32 + 16 + lo];
            #pragma unroll
            for (int r = 0; r < 4; ++r) {
                int row = wv*16 + hi*4 + r;
                float s0 = 1.f / (1.f + __expf(-(d0[r] + ba0)));
                float s1 = 1.f / (1.f + __expf(-(d1[r] + ba1)));
                float v0 = bf2f(*(const unsigned short*)(L + SF_O + row*256 + ((j*64 + lo*2) ^ (hi<<4))));
                float v1 = bf2f(*(const unsigned short*)(L + SF_O + row*256 + ((j*64 + (16+lo)*2) ^ (hi<<4))));
                wacc[0][r] += v0 * s0;
                wacc[1][r] += v1 * s1;
            }
        }
        __syncthreads();
        #pragma unroll
        for (int nt = 0; nt < 2; ++nt) {
            int col = nt*16 + lo;
            #pragma unroll
            for (int r = 0; r < 4; ++r) {
                int row = wv*16 + hi*4 + r;
                *(unsigned short*)(L + ASWS_O + ((col>>3)*64 + row)*16 + (col&7)*2) = f2bf(wacc[nt][r]);
            }
        }
    }
    __syncthreads();
    // stage wl1 (-> sf region) + wl2 (-> wz/watt region); sfeat MFMA -> ofs cols 64..127
    {
        const uint4* src1 = (const uint4*)(wq + 38912);
        uint4* dst1 = (uint4*)(L + SF_O);
        for (int idx = t; idx < 1024; idx += 256) dst1[idx] = src1[idx];
        const uint4* src2 = (const uint4*)(wq + 55296);
        uint4* dst2 = (uint4*)(L + WL2_O);
        for (int idx = t; idx < 512; idx += 256) dst2[idx] = src2[idx];

        bf16x8 af = *(const bf16x8*)(L + ASWS_O + (hi*64 + arow)*16);
        #pragma unroll
        for (int nt = 0; nt < 4; ++nt) {
            f32x4 d = (f32x4){0.f,0.f,0.f,0.f};
            bf16x8 bf = *(const bf16x8*)(L + WOT_O + (hi*64 + nt*16 + lo)*16);
            d = __builtin_amdgcn_mfma_f32_16x16x32_bf16(af, bf, d, 0,0,0);
            int col2 = 64 + nt*16 + lo;
            #pragma unroll
            for (int r = 0; r < 4; ++r) {
                int row = wv*16 + hi*4 + r;
                int byte = (((row << 8) + (col2 << 1)) ^ ((row & 7) << 4));
                *(unsigned short*)(L + OFS_O + byte) = f2bf(d[r]);
            }
        }
    }
    __syncthreads();

    // layer 1: h = relu(of @ W_l1), K=128
    f32x4 acc[4];
    #pragma unroll
    for (int nt = 0; nt < 4; ++nt) acc[nt] = (f32x4){0.f,0.f,0.f,0.f};
    #pragma unroll
    for (int kk = 0; kk < 4; ++kk) {
        int abyte = ((arow << 8) + ((kk*4 + hi) << 4)) ^ ((arow & 7) << 4);
        bf16x8 af = *(const bf16x8*)(L + OFS_O + abyte);
        #pragma unroll
        for (int nt = 0; nt < 4; ++nt) {
            int brow = nt*16 + lo;
            int bbyte = ((brow << 8) + ((kk*4 + hi) << 4)) ^ ((brow & 7) << 4);
            bf16x8 bf = *(const bf16x8*)(L + SF_O + bbyte);
            acc[nt] = __builtin_amdgcn_mfma_f32_16x16x32_bf16(af, bf, acc[nt], 0, 0, 0);
        }
    }
    #pragma unroll
    for (int nt = 0; nt < 4; ++nt) {
        #pragma unroll
        for (int r = 0; r < 4; ++r) {
            int row = wv*16 + hi*4 + r;
            int col = nt*16 + lo;
            int byte = ((row << 7) + (col << 1)) ^ ((row & 7) << 4);
            *(unsigned short*)(L + HS_O + byte) = f2bf(fmaxf(acc[nt][r], 0.f));
        }
    }
    __syncthreads();

    // layer 2: out = h @ W_l2 + b_l2
    f32x4 acc2[4];
    #pragma unroll
    for (int nt = 0; nt < 4; ++nt) acc2[nt] = (f32x4){0.f,0.f,0.f,0.f};
    #pragma unroll
    for (int kk = 0; kk < 2; ++kk) {
        int abyte = ((arow << 7) + ((kk*4 + hi) << 4)) ^ ((arow & 7) << 4);
        bf16x8 af = *(const bf16x8*)(L + HS_O + abyte);
        #pragma unroll
        for (int nt = 0; nt < 4; ++nt) {
            int brow = nt*16 + lo;
            int bbyte = ((brow << 7) + ((kk*4 + hi) << 4)) ^ ((brow & 7) << 4);
            bf16x8 bf = *(const bf16x8*)(L + WL2_O + bbyte);
            acc2[nt] = __builtin_amdgcn_mfma_f32_16x16x32_bf16(af, bf, acc2[nt], 0, 0, 0);
        }
    }
    #pragma unroll
    for (int nt = 0; nt < 4; ++nt) {
        int col = nt*16 + lo;
        float bl = b_l2[col];
        #pragma unroll
        for (int r = 0; r < 4; ++r) {
            int row = i0 + wv*16 + hi*4 + r;
            if (row < n) out[(size_t)row*64 + col] = acc2[nt][r] + bl;
        }
    }
}

extern "C" void kernel_launch(void* const* d_in, const int* in_sizes, int n_in,
                              void* d_out, int out_size, void* d_ws, size_t ws_size,
                              hipStream_t stream) {
    const float* x      = (const float*)d_in[0];
    const int*   coords = (const int*)  d_in[1];
    const int*   cinv   = (const int*)  d_in[2];
    const float* W_red  = (const float*)d_in[3];
    const float* b_red  = (const float*)d_in[4];
    const float* W_pool = (const float*)d_in[5];
    const float* b_pool = (const float*)d_in[6];
    const float* W_att  = (const float*)d_in[7];
    const float* b_att  = (const float*)d_in[8];
    const float* W_z    = (const float*)d_in[9];
    const float* W_out  = (const float*)d_in[10];
    const float* W_l1   = (const float*)d_in[11];
    const float* W_l2   = (const float*)d_in[12];
    const float* b_l2   = (const float*)d_in[13];
    float* out = (float*)d_out;
    int n = in_sizes[0] / 64;

    char* wsb = (char*)d_ws;
    unsigned int*   red32   = (unsigned int*)(wsb);
    unsigned short* red     = (unsigned short*)(wsb);
    unsigned int*   sums_pk = (unsigned int*)(wsb + SUMS_OFF);
    float*          cnt     = (float*)(wsb + CNT_OFF);
    unsigned short* att     = (unsigned short*)(wsb + ATT_OFF);
    char*           wq      = wsb + WQ_OFF;

    k0_wprep<<<124, 256, 0, stream>>>(W_red, W_pool, W_z, W_att, W_out, W_l1, W_l2, wq);
    hipMemsetAsync(sums_pk, 0, (size_t)SEG1 * 128ull, stream);
    hipMemsetAsync(cnt, 0, (size_t)SEG1 * 4ull, stream);

    k1_mfma<<<(n + 63) / 64, 256, 0, stream>>>(x, coords, wq, b_red, red32, sums_pk, cnt, n);
    k_pyramid<<<PYRB12, 256, 0, stream>>>(sums_pk, cnt);
    k_pyr3<<<1024, 256, 0, stream>>>(sums_pk, cnt);
    k2_mfma<<<K2BT, 256, 0, stream>>>(sums_pk, cnt, wq, b_pool, att);
    k3_fused<<<(n + 63) / 64, 256, 0, stream>>>(coords, cinv, att, red, wq, b_att, b_l2, out, n);
}

// Round 13
// 244.076 us; speedup vs baseline: 1.0547x; 1.0547x over previous
//
#include <hip/hip_runtime.h>
#include <hip/hip_bf16.h>

// Segment counts per scale: ps=2:(128,128,16) ps=4:(64,64,8) ps=6:(43,43,6) ps=8:(32,32,4), B=2
#define SEG1 524288
#define SEG2 589824
#define SEG3 612012
#define SEGT 620204

// k2 block mapping: blocks per scale = ceil(segCount/64) = {8192, 1024, 347, 128}
#define K2B0 8192
#define K2B1 9216
#define K2B2 9563
#define K2BT 9691

#define PYRB12 10968

// ws layout (BYTES):
//   red_bf16   @ 0           : 32,000,000 B
//   sums_bf16  @ 32,000,000  : 79,386,112 B (SEGT*64 bf16 packed)
//   cnt        @ 111,386,112 : 2,480,816 B
//   att_bf16   @ 113,866,928 : 39,693,056 B (end 153,559,984)
//   wq (pre-swizzled bf16 weights) @ 153,560,064 : 63,488 B
//   sfeat_bf16 aliases sums start (sums dead after k2)
#define SUMS_OFF 32000000ull
#define CNT_OFF  111386112ull
#define ATT_OFF  113866928ull
#define WQ_OFF   153560064ull
// wq sections: k1Bw 0 (8192) | k2Bs 8192 (16384, 4096/j) | wz 24576 (2048)
//   | watt 26624 (8192) | wot 34816 (4096) | wl1 38912 (16384) | wl2 55296 (8192)

typedef __attribute__((ext_vector_type(8))) __bf16 bf16x8;
typedef __attribute__((ext_vector_type(4))) float  f32x4;

__device__ __forceinline__ float bf2f(unsigned short u) {
    union { unsigned int i; float f; } v; v.i = ((unsigned int)u) << 16; return v.f;
}
__device__ __forceinline__ unsigned short f2bf(float f) {
    union { float f; unsigned int i; } v; v.f = f;
    unsigned int r = v.i + 0x7FFF + ((v.i >> 16) & 1);
    return (unsigned short)(r >> 16);
}
__device__ __forceinline__ void atom_pk_bf16(unsigned int* addr, unsigned int pk) {
    asm volatile("global_atomic_pk_add_bf16 %0, %1, off" :: "v"(addr), "v"(pk) : "memory");
}

__device__ __forceinline__ int seg0_of(int b, int cx, int cy, int cz) {
    return ((b*128 + (cx>>1))*128 + (cy>>1))*16 + (cz>>1);
}
__device__ __forceinline__ void seg4(int b, int cx, int cy, int cz, int* s) {
    s[0] =        ((b*128 + (cx>>1))*128 + (cy>>1))*16 + (cz>>1);
    s[1] = SEG1 + ((b*64  + (cx>>2))*64  + (cy>>2))*8  + (cz>>2);
    s[2] = SEG2 + ((b*43  + (cx/6 ))*43  + (cy/6 ))*6  + (cz/6 );
    s[3] = SEG3 + ((b*32  + (cx>>3))*32  + (cy>>3))*4  + (cz>>3);
}

// k0: convert + pre-swizzle all weights into wq.
__global__ __launch_bounds__(256) void k0_wprep(
    const float* __restrict__ W_red, const float* __restrict__ W_pool,
    const float* __restrict__ W_z, const float* __restrict__ W_att,
    const float* __restrict__ W_out, const float* __restrict__ W_l1,
    const float* __restrict__ W_l2, char* __restrict__ wq)
{
    int g = blockIdx.x*256 + threadIdx.x;
    if (g < 4096) {
        int idx = g; int k = idx>>6, c = idx&63;
        int byte = (((c<<7)+(k<<1)) ^ ((c&7)<<4));
        *(unsigned short*)(wq + byte) = f2bf(W_red[idx]);
    } else if (g < 12288) {
        int idx = g - 4096; int j = idx>>11, r2 = idx&2047, k = r2>>5, c = r2&31;
        int byte = j*4096 + (((c<<7)+(k<<1)) ^ ((c&7)<<4));
        *(unsigned short*)(wq + 8192 + byte) = f2bf(W_pool[idx]);
    } else if (g < 13312) {
        int idx = g - 12288; int k = idx>>5, c = idx&31;
        *(unsigned short*)(wq + 24576 + ((k>>3)*32+c)*16 + (k&7)*2) = f2bf(W_z[idx]);
    } else if (g < 17408) {
        int idx = g - 13312; int j = idx>>10, rem = idx&1023, k = rem>>5, c = rem&31;
        *(unsigned short*)(wq + 26624 + j*2048 + ((k>>3)*32+c)*16 + (k&7)*2) = f2bf(W_att[idx]);
    } else if (g < 19456) {
        int idx = g - 17408; int k = idx>>6, c = idx&63;
        *(unsigned short*)(wq + 34816 + ((k>>3)*64+c)*16 + (k&7)*2) = f2bf(W_out[idx]);
    } else if (g < 27648) {
        int idx = g - 19456; int k = idx>>6, c = idx&63;
        int byte = (((c<<8)+(k<<1)) ^ ((c&7)<<4));
        *(unsigned short*)(wq + 38912 + byte) = f2bf(W_l1[idx]);
    } else if (g < 31744) {
        int idx = g - 27648; int k = idx>>6, c = idx&63;
        int byte = (((c<<7)+(k<<1)) ^ ((c&7)<<4));
        *(unsigned short*)(wq + 55296 + byte) = f2bf(W_l2[idx]);
    }
}

// k1 via MFMA: red = relu(x@W_red+b) bf16; pk-bf16 atomic scatter to scale-0 only.
__global__ __launch_bounds__(256) void k1_mfma(
    const float* __restrict__ x, const int* __restrict__ coords,
    const char* __restrict__ wq, const float* __restrict__ b_red,
    unsigned int* __restrict__ red32, unsigned int* __restrict__ sums_pk,
    float* __restrict__ cnt, int n)
{
    __shared__ uint4 Ax4[512];
    __shared__ uint4 Bw4[512];
    __shared__ uint4 Rt4[512];
    __shared__ int segl[64];
    char* Ax = (char*)Ax4; char* Bw = (char*)Bw4; char* Rt = (char*)Rt4;

    int t = threadIdx.x;
    int i0 = blockIdx.x * 64;

    if (t < 64) {
        int r = i0 + t;
        if (r < n) {
            int4 cv = *(const int4*)&coords[(size_t)r*4];
            int s0 = seg0_of(cv.x, cv.y, cv.z, cv.w);
            segl[t] = s0;
            unsafeAtomicAdd(&cnt[s0], 1.f);
        } else segl[t] = -1;
    }
    {
        const uint4* src = (const uint4*)wq;
        for (int idx = t; idx < 512; idx += 256) Bw4[idx] = src[idx];
    }
    #pragma unroll
    for (int i2 = 0; i2 < 2; ++i2) {
        int idx = i2*256 + t;
        int row = idx >> 3, kc = idx & 7;
        int r = i0 + row;
        unsigned short u[8];
        if (r < n) {
            float4 v0 = *(const float4*)&x[(size_t)r*64 + kc*8];
            float4 v1 = *(const float4*)&x[(size_t)r*64 + kc*8 + 4];
            u[0]=f2bf(v0.x); u[1]=f2bf(v0.y); u[2]=f2bf(v0.z); u[3]=f2bf(v0.w);
            u[4]=f2bf(v1.x); u[5]=f2bf(v1.y); u[6]=f2bf(v1.z); u[7]=f2bf(v1.w);
        } else {
            #pragma unroll
            for (int q = 0; q < 8; ++q) u[q] = 0;
        }
        int byte = ((row << 7) + (kc << 4)) ^ ((row & 7) << 4);
        *(uint4*)(Ax + byte) = *(const uint4*)u;
    }
    __syncthreads();

    int lane = t & 63, wv = t >> 6;
    int hi = lane >> 4, lo = lane & 15;
    int arow = wv*16 + lo;

    f32x4 acc[4];
    #pragma unroll
    for (int nt = 0; nt < 4; ++nt) acc[nt] = (f32x4){0.f,0.f,0.f,0.f};
    #pragma unroll
    for (int kk = 0; kk < 2; ++kk) {
        int abyte = ((arow << 7) + ((kk*4 + hi) << 4)) ^ ((arow & 7) << 4);
        bf16x8 af = *(const bf16x8*)(Ax + abyte);
        #pragma unroll
        for (int nt = 0; nt < 4; ++nt) {
            int brow = nt*16 + lo;
            int bbyte = ((brow << 7) + ((kk*4 + hi) << 4)) ^ ((brow & 7) << 4);
            bf16x8 bf = *(const bf16x8*)(Bw + bbyte);
            acc[nt] = __builtin_amdgcn_mfma_f32_16x16x32_bf16(af, bf, acc[nt], 0, 0, 0);
        }
    }
    #pragma unroll
    for (int nt = 0; nt < 4; ++nt) {
        int col = nt*16 + lo;
        float bb = b_red[col];
        #pragma unroll
        for (int r = 0; r < 4; ++r) {
            int row = wv*16 + hi*4 + r;
            int byte = ((row << 7) + (col << 1)) ^ ((row & 7) << 4);
            *(unsigned short*)(Rt + byte) = f2bf(fmaxf(acc[nt][r] + bb, 0.f));
        }
    }
    __syncthreads();

    #pragma unroll
    for (int i2 = 0; i2 < 2; ++i2) {
        int idx = i2*256 + t;
        int row = idx >> 3, ck = idx & 7;
        int r = i0 + row;
        if (r < n) {
            int byte = ((row << 7) + (ck << 4)) ^ ((row & 7) << 4);
            *(uint4*)&red32[(size_t)r*32 + ck*4] = *(const uint4*)(Rt + byte);
        }
    }
    {
        int half = t >> 5, c = t & 31;
        #pragma unroll
        for (int i2 = 0; i2 < 8; ++i2) {
            int p = i2*8 + half;
            int s0_ = segl[p];
            if (s0_ >= 0) {
                int byte = ((p << 7) + (c << 2)) ^ ((p & 7) << 4);
                unsigned int pk = *(const unsigned int*)(Rt + byte);
                atom_pk_bf16(&sums_pk[(size_t)s0_*32 + c], pk);
            }
        }
    }
    asm volatile("s_waitcnt vmcnt(0)" ::: "memory");
}

// k_pyramid: scales 1+2 from scale-0; skip empty children (cnt==0 rows are exact zeros).
__global__ __launch_bounds__(256) void k_pyramid(
    unsigned int* __restrict__ sums_pk, float* __restrict__ cnt)
{
    int t = threadIdx.x;
    int lane = t & 31;
    int cg = blockIdx.x * 8 + (t >> 5);

    float a0 = 0.f, a1 = 0.f, ca = 0.f;
    int outSeg = -1;

    if (cg < 65536) {                       // scale 1 (ps=4): 8 children
        int r1 = cg;
        int qz = r1 & 7, qy = (r1 >> 3) & 63, qx = (r1 >> 9) & 63, b = r1 >> 15;
        #pragma unroll
        for (int d = 0; d < 8; ++d) {
            int x2 = 2*qx + (d>>2), y2 = 2*qy + ((d>>1)&1), z2 = 2*qz + (d&1);
            int child = ((b*128 + x2)*128 + y2)*16 + z2;
            float cc = cnt[child];
            if (cc > 0.f) {
                unsigned int v = sums_pk[(size_t)child*32 + lane];
                a0 += bf2f((unsigned short)(v & 0xffff));
                a1 += bf2f((unsigned short)(v >> 16));
                ca += cc;
            }
        }
        outSeg = SEG1 + r1;
    } else {                                // scale 2 (ps=6): <=27 children
        int r2 = cg - 65536;
        if (r2 < 22188) {
            int z6 = r2 % 6; int tmp = r2 / 6;
            int y6 = tmp % 43; tmp /= 43;
            int x6 = tmp % 43; int b = tmp / 43;
            for (int dx = 0; dx < 3; ++dx) {
                int x2 = 3*x6 + dx; if (x2 >= 128) break;
                for (int dy = 0; dy < 3; ++dy) {
                    int y2 = 3*y6 + dy; if (y2 >= 128) break;
                    for (int dz = 0; dz < 3; ++dz) {
                        int z2 = 3*z6 + dz; if (z2 >= 16) break;
                        int child = ((b*128 + x2)*128 + y2)*16 + z2;
                        float cc = cnt[child];
                        if (cc > 0.f) {
                            unsigned int v = sums_pk[(size_t)child*32 + lane];
                            a0 += bf2f((unsigned short)(v & 0xffff));
                            a1 += bf2f((unsigned short)(v >> 16));
                            ca += cc;
                        }
                    }
                }
            }
            outSeg = SEG2 + r2;
        }
    }

    if (outSeg >= 0) {
        unsigned int pk = (unsigned int)f2bf(a0) | ((unsigned int)f2bf(a1) << 16);
        sums_pk[(size_t)outSeg*32 + lane] = pk;
        if (lane == 0) cnt[outSeg] = ca;
    }
}

// k_pyr3: scale 3 (ps=8) from scale-1 children (exact 2x2x2 nesting).
__global__ __launch_bounds__(256) void k_pyr3(
    unsigned int* __restrict__ sums_pk, float* __restrict__ cnt)
{
    int t = threadIdx.x;
    int lane = t & 31;
    int r3 = blockIdx.x * 8 + (t >> 5);
    int z8 = r3 & 3, y8 = (r3 >> 2) & 31, x8 = (r3 >> 7) & 31, b = r3 >> 12;
    float a0 = 0.f, a1 = 0.f, ca = 0.f;
    #pragma unroll
    for (int d = 0; d < 8; ++d) {
        int qx = 2*x8 + (d>>2), qy = 2*y8 + ((d>>1)&1), qz = 2*z8 + (d&1);
        int child = SEG1 + ((b*64 + qx)*64 + qy)*8 + qz;
        unsigned int v = sums_pk[(size_t)child*32 + lane];
        a0 += bf2f((unsigned short)(v & 0xffff));
        a1 += bf2f((unsigned short)(v >> 16));
        if (lane == 0) ca += cnt[child];
    }
    unsigned int pk = (unsigned int)f2bf(a0) | ((unsigned int)f2bf(a1) << 16);
    sums_pk[(size_t)(SEG3 + r3)*32 + lane] = pk;
    if (lane == 0) cnt[SEG3 + r3] = ca;
}

// k2 via MFMA with empty-segment skip (load & store predicated on cnt>0).
__global__ __launch_bounds__(256) void k2_mfma(
    const unsigned int* __restrict__ sums_pk, const float* __restrict__ cnt,
    const char* __restrict__ wq, const float* __restrict__ b_pool,
    unsigned short* __restrict__ att)
{
    __shared__ uint4 As4[512];
    __shared__ uint4 Bs4[256];
    char* As = (char*)As4; char* Bs = (char*)Bs4;

    int t = threadIdx.x;
    int bid = blockIdx.x;
    int j, rel;
    if (bid < K2B0)      { j = 0; rel = bid; }
    else if (bid < K2B1) { j = 1; rel = bid - K2B0; }
    else if (bid < K2B2) { j = 2; rel = bid - K2B1; }
    else                 { j = 3; rel = bid - K2B2; }
    const int segStartT[4] = {0, SEG1, SEG2, SEG3};
    const int segEndT[4]   = {SEG1, SEG2, SEG3, SEGT};
    int s0 = segStartT[j] + rel * 64;
    int sEnd = segEndT[j];

    {
        const uint4* src = (const uint4*)(wq + 8192 + j*4096);
        for (int idx = t; idx < 256; idx += 256) Bs4[idx] = src[idx];
    }
    #pragma unroll
    for (int i = 0; i < 4; ++i) {
        int idx = i*256 + t;
        int p = idx >> 4, c4 = idx & 15;
        int s = s0 + p;
        unsigned int lo = 0, hi2 = 0; float cv = 0.f;
        if (s < sEnd) cv = cnt[s];
        if (cv > 0.f) {
            uint2 v = *(const uint2*)&sums_pk[(size_t)s*32 + c4*2];
            lo = v.x; hi2 = v.y;
        }
        float inv = (cv > 0.f) ? 1.f / cv : 0.f;
        unsigned short u[4] = { f2bf(bf2f((unsigned short)(lo & 0xffff))*inv),
                                f2bf(bf2f((unsigned short)(lo >> 16))*inv),
                                f2bf(bf2f((unsigned short)(hi2 & 0xffff))*inv),
                                f2bf(bf2f((unsigned short)(hi2 >> 16))*inv) };
        int byte = ((p << 7) + (c4 << 3)) ^ ((p & 7) << 4);
        *(uint2*)(As + byte) = *(const uint2*)u;
    }
    __syncthreads();

    int lane = t & 63, wv = t >> 6;
    int hi = lane >> 4, lo = lane & 15;
    int arow = wv*16 + lo;

    f32x4 acc[2];
    acc[0] = (f32x4){0.f,0.f,0.f,0.f};
    acc[1] = (f32x4){0.f,0.f,0.f,0.f};
    #pragma unroll
    for (int kk = 0; kk < 2; ++kk) {
        int abyte = ((arow << 7) + ((kk*4 + hi) << 4)) ^ ((arow & 7) << 4);
        bf16x8 af = *(const bf16x8*)(As + abyte);
        #pragma unroll
        for (int nt = 0; nt < 2; ++nt) {
            int brow = nt*16 + lo;
            int bbyte = ((brow << 7) + ((kk*4 + hi) << 4)) ^ ((brow & 7) << 4);
            bf16x8 bf = *(const bf16x8*)(Bs + bbyte);
            acc[nt] = __builtin_amdgcn_mfma_f32_16x16x32_bf16(af, bf, acc[nt], 0, 0, 0);
        }
    }
    #pragma unroll
    for (int nt = 0; nt < 2; ++nt) {
        int col = nt*16 + lo;
        float bp = b_pool[j*32 + col];
        #pragma unroll
        for (int r = 0; r < 4; ++r) {
            int s = s0 + wv*16 + hi*4 + r;
            if (s < sEnd && cnt[s] > 0.f)
                att[(size_t)s*32 + col] = f2bf(fmaxf(acc[nt][r] + bp, 0.f));
        }
    }
}

// k3a via MFMA with fused shfl-ssum; As/Ws aliased; pre-swizzled weights.
__global__ __launch_bounds__(256) void k3a_mfma(
    const int* __restrict__ coords, const unsigned short* __restrict__ att,
    const char* __restrict__ wq, const float* __restrict__ b_att,
    unsigned short* __restrict__ sfeat, int n)
{
    __shared__ uint4 wcomb4[896];   // wz(2KB) + watt(8KB) + wot(4KB), 14KB
    __shared__ unsigned short sf[8192];  // 16KB
    __shared__ unsigned short AsWs[2048]; // 4KB (As then Ws)
    __shared__ unsigned short Fz[2048];   // 4KB
    __shared__ int segl[64][4];
    char* wzp  = (char*)wcomb4;
    char* wattp = (char*)wcomb4 + 2048;
    char* wotp = (char*)wcomb4 + 10240;

    int t = threadIdx.x;
    int i0 = blockIdx.x * 64;
    if (t < 64) {
        int r = i0 + t; if (r >= n) r = n - 1;
        int sg[4]; seg4(coords[r*4], coords[r*4+1], coords[r*4+2], coords[r*4+3], sg);
        segl[t][0]=sg[0]; segl[t][1]=sg[1]; segl[t][2]=sg[2]; segl[t][3]=sg[3];
    }
    {
        const uint4* src = (const uint4*)(wq + 24576);
        for (int idx = t; idx < 896; idx += 256) wcomb4[idx] = src[idx];
    }
    __syncthreads();

    // gather att + fused ssum (shfl over j in lane bits [3:2])
    #pragma unroll
    for (int i = 0; i < 4; ++i) {
        int idx = i*256 + t;
        int p = idx >> 4, j = (idx >> 2) & 3, ck = idx & 3;
        int s = segl[p][j];
        uint4 v = *(const uint4*)(att + (size_t)s*32 + ck*8);
        int off = (j*64 + ck*16) ^ (((p>>2)&3) << 4);
        *(uint4*)((char*)sf + p*256 + off) = v;
        unsigned int w_[4] = {v.x, v.y, v.z, v.w};
        float f[8];
        #pragma unroll
        for (int q = 0; q < 4; ++q) {
            f[2*q]   = bf2f((unsigned short)(w_[q] & 0xffff));
            f[2*q+1] = bf2f((unsigned short)(w_[q] >> 16));
        }
        #pragma unroll
        for (int q = 0; q < 8; ++q) {
            f[q] += __shfl_xor(f[q], 4);
            f[q] += __shfl_xor(f[q], 8);
        }
        if (j == 0) {
            unsigned short u8[8];
            #pragma unroll
            for (int q = 0; q < 8; ++q) u8[q] = f2bf(f[q]);
            *(uint4*)((char*)AsWs + (ck*64 + p)*16) = *(const uint4*)u8;
        }
    }
    __syncthreads();

    int lane = t & 63, wv = t >> 6;
    int hi = lane >> 4, lo = lane & 15;
    int arow = wv*16 + lo;

    // fz = relu(ssum @ Wz), K=32
    {
        bf16x8 af = *(const bf16x8*)((char*)AsWs + (hi*64 + arow)*16);
        f32x4 d0 = (f32x4){0.f,0.f,0.f,0.f}, d1 = (f32x4){0.f,0.f,0.f,0.f};
        bf16x8 b0 = *(const bf16x8*)(wzp + (hi*32 + lo)*16);
        bf16x8 b1 = *(const bf16x8*)(wzp + (hi*32 + 16 + lo)*16);
        d0 = __builtin_amdgcn_mfma_f32_16x16x32_bf16(af, b0, d0, 0,0,0);
        d1 = __builtin_amdgcn_mfma_f32_16x16x32_bf16(af, b1, d1, 0,0,0);
        #pragma unroll
        for (int r = 0; r < 4; ++r) {
            int row = wv*16 + hi*4 + r;
            int c0 = lo, c1 = 16 + lo;
            *(unsigned short*)((char*)Fz + ((c0>>3)*64 + row)*16 + (c0&7)*2) = f2bf(fmaxf(d0[r], 0.f));
            *(unsigned short*)((char*)Fz + ((c1>>3)*64 + row)*16 + (c1&7)*2) = f2bf(fmaxf(d1[r], 0.f));
        }
    }
    __syncthreads();
    // wsum = sum_j sf_j * sigmoid(fz @ Watt_j + b_att_j)  -> AsWs (As dead)
    {
        float wacc[2][4] = {{0.f,0.f,0.f,0.f},{0.f,0.f,0.f,0.f}};
        bf16x8 af = *(const bf16x8*)((char*)Fz + (hi*64 + arow)*16);
        #pragma unroll
        for (int j = 0; j < 4; ++j) {
            f32x4 d0 = (f32x4){0.f,0.f,0.f,0.f}, d1 = (f32x4){0.f,0.f,0.f,0.f};
            bf16x8 b0 = *(const bf16x8*)(wattp + j*2048 + (hi*32 + lo)*16);
            bf16x8 b1 = *(const bf16x8*)(wattp + j*2048 + (hi*32 + 16 + lo)*16);
            d0 = __builtin_amdgcn_mfma_f32_16x16x32_bf16(af, b0, d0, 0,0,0);
            d1 = __builtin_amdgcn_mfma_f32_16x16x32_bf16(af, b1, d1, 0,0,0);
            float ba0 = b_att[j*32 + lo], ba1 = b_att[j*32 + 16 + lo];
            #pragma unroll
            for (int r = 0; r < 4; ++r) {
                int row = wv*16 + hi*4 + r;
                float s0 = 1.f / (1.f + __expf(-(d0[r] + ba0)));
                float s1 = 1.f / (1.f + __expf(-(d1[r] + ba1)));
                float v0 = bf2f(*(const unsigned short*)((char*)sf + row*256 + ((j*64 + lo*2) ^ (hi<<4))));
                float v1 = bf2f(*(const unsigned short*)((char*)sf + row*256 + ((j*64 + (16+lo)*2) ^ (hi<<4))));
                wacc[0][r] += v0 * s0;
                wacc[1][r] += v1 * s1;
            }
        }
        __syncthreads();
        #pragma unroll
        for (int nt = 0; nt < 2; ++nt) {
            int col = nt*16 + lo;
            #pragma unroll
            for (int r = 0; r < 4; ++r) {
                int row = wv*16 + hi*4 + r;
                *(unsigned short*)((char*)AsWs + ((col>>3)*64 + row)*16 + (col&7)*2) = f2bf(wacc[nt][r]);
            }
        }
    }
    __syncthreads();
    // sfeat = wsum @ W_out, K=32, N=64
    {
        bf16x8 af = *(const bf16x8*)((char*)AsWs + (hi*64 + arow)*16);
        #pragma unroll
        for (int nt = 0; nt < 4; ++nt) {
            f32x4 d = (f32x4){0.f,0.f,0.f,0.f};
            bf16x8 bf = *(const bf16x8*)(wotp + (hi*64 + nt*16 + lo)*16);
            d = __builtin_amdgcn_mfma_f32_16x16x32_bf16(af, bf, d, 0,0,0);
            int col = nt*16 + lo;
            #pragma unroll
            for (int r = 0; r < 4; ++r) {
                int row = i0 + wv*16 + hi*4 + r;
                if (row < n) sfeat[(size_t)row*64 + col] = f2bf(d[r]);
            }
        }
    }
}

__global__ __launch_bounds__(256) void k3b_mfma(
    const int* __restrict__ cinv,
    const unsigned short* __restrict__ red, const unsigned short* __restrict__ sfeat,
    const char* __restrict__ wq, const float* __restrict__ b_l2,
    float* __restrict__ out, int n)
{
    __shared__ uint4 ofs4[1024];  // 16KB
    __shared__ uint4 wl4[1536];   // wl1 16KB + wl2 8KB
    __shared__ uint4 hs4[512];    // 8KB
    __shared__ int rl[64];
    char* ofs = (char*)ofs4;
    char* wl1 = (char*)wl4;
    char* wl2 = (char*)wl4 + 16384;
    char* hs  = (char*)hs4;

    int t = threadIdx.x;
    int i0 = blockIdx.x * 64;
    if (t < 64) { int i = i0 + t; rl[t] = cinv[(i < n) ? i : (n-1)]; }

    {
        const uint4* src = (const uint4*)(wq + 38912);
        for (int idx = t; idx < 1536; idx += 256) wl4[idx] = src[idx];
    }
    __syncthreads();
    for (int idx = t; idx < 1024; idx += 256) {
        int p = idx >> 4, c = idx & 15;
        int r = rl[p];
        const unsigned short* src = (c < 8) ? (red + (size_t)r*64 + c*8)
                                            : (sfeat + (size_t)r*64 + (c-8)*8);
        uint4 v = *(const uint4*)src;
        int byte = ((p << 8) + (c << 4)) ^ ((p & 7) << 4);
        *(uint4*)(ofs + byte) = v;
    }
    __syncthreads();

    int lane = t & 63, wv = t >> 6;
    int hi = lane >> 4, lo = lane & 15;
    int arow = wv*16 + lo;

    f32x4 acc[4];
    #pragma unroll
    for (int nt = 0; nt < 4; ++nt) acc[nt] = (f32x4){0.f,0.f,0.f,0.f};
    #pragma unroll
    for (int kk = 0; kk < 4; ++kk) {
        int abyte = ((arow << 8) + ((kk*4 + hi) << 4)) ^ ((arow & 7) << 4);
        bf16x8 af = *(const bf16x8*)(ofs + abyte);
        #pragma unroll
        for (int nt = 0; nt < 4; ++nt) {
            int brow = nt*16 + lo;
            int bbyte = ((brow << 8) + ((kk*4 + hi) << 4)) ^ ((brow & 7) << 4);
            bf16x8 bf = *(const bf16x8*)(wl1 + bbyte);
            acc[nt] = __builtin_amdgcn_mfma_f32_16x16x32_bf16(af, bf, acc[nt], 0, 0, 0);
        }
    }
    #pragma unroll
    for (int nt = 0; nt < 4; ++nt) {
        #pragma unroll
        for (int r = 0; r < 4; ++r) {
            int row = wv*16 + hi*4 + r;
            int col = nt*16 + lo;
            int byte = ((row << 7) + (col << 1)) ^ ((row & 7) << 4);
            *(unsigned short*)(hs + byte) = f2bf(fmaxf(acc[nt][r], 0.f));
        }
    }
    __syncthreads();

    f32x4 acc2[4];
    #pragma unroll
    for (int nt = 0; nt < 4; ++nt) acc2[nt] = (f32x4){0.f,0.f,0.f,0.f};
    #pragma unroll
    for (int kk = 0; kk < 2; ++kk) {
        int abyte = ((arow << 7) + ((kk*4 + hi) << 4)) ^ ((arow & 7) << 4);
        bf16x8 af = *(const bf16x8*)(hs + abyte);
        #pragma unroll
        for (int nt = 0; nt < 4; ++nt) {
            int brow = nt*16 + lo;
            int bbyte = ((brow << 7) + ((kk*4 + hi) << 4)) ^ ((brow & 7) << 4);
            bf16x8 bf = *(const bf16x8*)(wl2 + bbyte);
            acc2[nt] = __builtin_amdgcn_mfma_f32_16x16x32_bf16(af, bf, acc2[nt], 0, 0, 0);
        }
    }
    #pragma unroll
    for (int nt = 0; nt < 4; ++nt) {
        int col = nt*16 + lo;
        float bl = b_l2[col];
        #pragma unroll
        for (int r = 0; r < 4; ++r) {
            int row = i0 + wv*16 + hi*4 + r;
            if (row < n) out[(size_t)row*64 + col] = acc2[nt][r] + bl;
        }
    }
}

extern "C" void kernel_launch(void* const* d_in, const int* in_sizes, int n_in,
                              void* d_out, int out_size, void* d_ws, size_t ws_size,
                              hipStream_t stream) {
    const float* x      = (const float*)d_in[0];
    const int*   coords = (const int*)  d_in[1];
    const int*   cinv   = (const int*)  d_in[2];
    const float* W_red  = (const float*)d_in[3];
    const float* b_red  = (const float*)d_in[4];
    const float* W_pool = (const float*)d_in[5];
    const float* b_pool = (const float*)d_in[6];
    const float* W_att  = (const float*)d_in[7];
    const float* b_att  = (const float*)d_in[8];
    const float* W_z    = (const float*)d_in[9];
    const float* W_out  = (const float*)d_in[10];
    const float* W_l1   = (const float*)d_in[11];
    const float* W_l2   = (const float*)d_in[12];
    const float* b_l2   = (const float*)d_in[13];
    float* out = (float*)d_out;
    int n = in_sizes[0] / 64;

    char* wsb = (char*)d_ws;
    unsigned int*   red32   = (unsigned int*)(wsb);
    unsigned short* red     = (unsigned short*)(wsb);
    unsigned int*   sums_pk = (unsigned int*)(wsb + SUMS_OFF);
    float*          cnt     = (float*)(wsb + CNT_OFF);
    unsigned short* att     = (unsigned short*)(wsb + ATT_OFF);
    char*           wq      = wsb + WQ_OFF;
    unsigned short* sfeat   = (unsigned short*)(wsb + SUMS_OFF);  // alias: sums dead after k2

    k0_wprep<<<124, 256, 0, stream>>>(W_red, W_pool, W_z, W_att, W_out, W_l1, W_l2, wq);
    hipMemsetAsync(sums_pk, 0, (size_t)SEG1 * 128ull, stream);
    hipMemsetAsync(cnt, 0, (size_t)SEG1 * 4ull, stream);

    k1_mfma<<<(n + 63) / 64, 256, 0, stream>>>(x, coords, wq, b_red, red32, sums_pk, cnt, n);
    k_pyramid<<<PYRB12, 256, 0, stream>>>(sums_pk, cnt);
    k_pyr3<<<1024, 256, 0, stream>>>(sums_pk, cnt);
    k2_mfma<<<K2BT, 256, 0, stream>>>(sums_pk, cnt, wq, b_pool, att);
    k3a_mfma<<<(n + 63) / 64, 256, 0, stream>>>(coords, att, wq, b_att, sfeat, n);
    k3b_mfma<<<(n + 63) / 64, 256, 0, stream>>>(cinv, red, sfeat, wq, b_l2, out, n);
}

// Round 14
// 217.794 us; speedup vs baseline: 1.1819x; 1.1207x over previous
//
#include <hip/hip_runtime.h>
#include <hip/hip_bf16.h>

// Segment counts per scale: ps=2:(128,128,16) ps=4:(64,64,8) ps=6:(43,43,6) ps=8:(32,32,4), B=2
#define SEG1 524288
#define SEG2 589824
#define SEG3 612012
#define SEGT 620204

// k2 block mapping: blocks per scale = ceil(segCount/64) = {8192, 1024, 347, 128}
#define K2B0 8192
#define K2B1 9216
#define K2B2 9563
#define K2BT 9691

#define PYRB12 10968

// ws layout (BYTES):
//   red_bf16   @ 0           : 32,000,000 B
//   sums_bf16  @ 32,000,000  : 79,386,112 B (SEGT*64 bf16 packed)
//   cnt        @ 111,386,112 : 2,480,816 B
//   att_bf16   @ 113,866,928 : 39,693,056 B (end 153,559,984)
//   wq (pre-swizzled bf16 weights) @ 153,560,064 : 63,488 B
//   sfeat_bf16 aliases sums start (sums dead after k2)
#define SUMS_OFF 32000000ull
#define CNT_OFF  111386112ull
#define ATT_OFF  113866928ull
#define WQ_OFF   153560064ull
// wq sections: k1Bw 0 (8192) | k2Bs 8192 (16384, 4096/j) | wz 24576 (2048)
//   | watt 26624 (8192) | wot 34816 (4096) | wl1 38912 (16384) | wl2 55296 (8192)

typedef __attribute__((ext_vector_type(8))) __bf16 bf16x8;
typedef __attribute__((ext_vector_type(4))) float  f32x4;

__device__ __forceinline__ float bf2f(unsigned short u) {
    union { unsigned int i; float f; } v; v.i = ((unsigned int)u) << 16; return v.f;
}
__device__ __forceinline__ unsigned short f2bf(float f) {
    union { float f; unsigned int i; } v; v.f = f;
    unsigned int r = v.i + 0x7FFF + ((v.i >> 16) & 1);
    return (unsigned short)(r >> 16);
}
__device__ __forceinline__ void atom_pk_bf16(unsigned int* addr, unsigned int pk) {
    asm volatile("global_atomic_pk_add_bf16 %0, %1, off" :: "v"(addr), "v"(pk) : "memory");
}

__device__ __forceinline__ int seg0_of(int b, int cx, int cy, int cz) {
    return ((b*128 + (cx>>1))*128 + (cy>>1))*16 + (cz>>1);
}
__device__ __forceinline__ void seg4(int b, int cx, int cy, int cz, int* s) {
    s[0] =        ((b*128 + (cx>>1))*128 + (cy>>1))*16 + (cz>>1);
    s[1] = SEG1 + ((b*64  + (cx>>2))*64  + (cy>>2))*8  + (cz>>2);
    s[2] = SEG2 + ((b*43  + (cx/6 ))*43  + (cy/6 ))*6  + (cz/6 );
    s[3] = SEG3 + ((b*32  + (cx>>3))*32  + (cy>>3))*4  + (cz>>3);
}

// k0: convert + pre-swizzle all weights into wq.
__global__ __launch_bounds__(256) void k0_wprep(
    const float* __restrict__ W_red, const float* __restrict__ W_pool,
    const float* __restrict__ W_z, const float* __restrict__ W_att,
    const float* __restrict__ W_out, const float* __restrict__ W_l1,
    const float* __restrict__ W_l2, char* __restrict__ wq)
{
    int g = blockIdx.x*256 + threadIdx.x;
    if (g < 4096) {
        int idx = g; int k = idx>>6, c = idx&63;
        int byte = (((c<<7)+(k<<1)) ^ ((c&7)<<4));
        *(unsigned short*)(wq + byte) = f2bf(W_red[idx]);
    } else if (g < 12288) {
        int idx = g - 4096; int j = idx>>11, r2 = idx&2047, k = r2>>5, c = r2&31;
        int byte = j*4096 + (((c<<7)+(k<<1)) ^ ((c&7)<<4));
        *(unsigned short*)(wq + 8192 + byte) = f2bf(W_pool[idx]);
    } else if (g < 13312) {
        int idx = g - 12288; int k = idx>>5, c = idx&31;
        *(unsigned short*)(wq + 24576 + ((k>>3)*32+c)*16 + (k&7)*2) = f2bf(W_z[idx]);
    } else if (g < 17408) {
        int idx = g - 13312; int j = idx>>10, rem = idx&1023, k = rem>>5, c = rem&31;
        *(unsigned short*)(wq + 26624 + j*2048 + ((k>>3)*32+c)*16 + (k&7)*2) = f2bf(W_att[idx]);
    } else if (g < 19456) {
        int idx = g - 17408; int k = idx>>6, c = idx&63;
        *(unsigned short*)(wq + 34816 + ((k>>3)*64+c)*16 + (k&7)*2) = f2bf(W_out[idx]);
    } else if (g < 27648) {
        int idx = g - 19456; int k = idx>>6, c = idx&63;
        int byte = (((c<<8)+(k<<1)) ^ ((c&7)<<4));
        *(unsigned short*)(wq + 38912 + byte) = f2bf(W_l1[idx]);
    } else if (g < 31744) {
        int idx = g - 27648; int k = idx>>6, c = idx&63;
        int byte = (((c<<7)+(k<<1)) ^ ((c&7)<<4));
        *(unsigned short*)(wq + 55296 + byte) = f2bf(W_l2[idx]);
    }
}

// k1 via MFMA: A-fragments straight from global x (fp32->bf16 in regs);
// red = relu(x@W_red+b) bf16; pk-bf16 atomic scatter to scale-0 only.
__global__ __launch_bounds__(256) void k1_mfma(
    const float* __restrict__ x, const int* __restrict__ coords,
    const char* __restrict__ wq, const float* __restrict__ b_red,
    unsigned int* __restrict__ red32, unsigned int* __restrict__ sums_pk,
    float* __restrict__ cnt, int n)
{
    __shared__ uint4 Bw4[512];   // W_red^T bf16 swizzled, 8KB
    __shared__ uint4 Rt4[512];   // red bf16 swizzled, 8KB
    __shared__ int segl[64];
    char* Bw = (char*)Bw4; char* Rt = (char*)Rt4;

    int t = threadIdx.x;
    int i0 = blockIdx.x * 64;

    if (t < 64) {
        int r = i0 + t;
        if (r < n) {
            int4 cv = *(const int4*)&coords[(size_t)r*4];
            int s0 = seg0_of(cv.x, cv.y, cv.z, cv.w);
            segl[t] = s0;
            unsafeAtomicAdd(&cnt[s0], 1.f);
        } else segl[t] = -1;
    }
    {
        const uint4* src = (const uint4*)wq;
        Bw4[t] = src[t];
        Bw4[t + 256] = src[t + 256];
    }
    __syncthreads();

    int lane = t & 63, wv = t >> 6;
    int hi = lane >> 4, lo = lane & 15;
    int arow = wv*16 + lo;
    int grow = i0 + arow;

    // A fragments direct from global x: row grow, floats kk*32 + hi*8 .. +8
    bf16x8 afr[2];
    #pragma unroll
    for (int kk = 0; kk < 2; ++kk) {
        unsigned short u[8];
        if (grow < n) {
            const float* xp = x + (size_t)grow*64 + kk*32 + hi*8;
            float4 v0 = *(const float4*)xp;
            float4 v1 = *(const float4*)(xp + 4);
            u[0]=f2bf(v0.x); u[1]=f2bf(v0.y); u[2]=f2bf(v0.z); u[3]=f2bf(v0.w);
            u[4]=f2bf(v1.x); u[5]=f2bf(v1.y); u[6]=f2bf(v1.z); u[7]=f2bf(v1.w);
        } else {
            #pragma unroll
            for (int q = 0; q < 8; ++q) u[q] = 0;
        }
        afr[kk] = *(const bf16x8*)u;
    }

    f32x4 acc[4];
    #pragma unroll
    for (int nt = 0; nt < 4; ++nt) acc[nt] = (f32x4){0.f,0.f,0.f,0.f};
    #pragma unroll
    for (int kk = 0; kk < 2; ++kk) {
        #pragma unroll
        for (int nt = 0; nt < 4; ++nt) {
            int brow = nt*16 + lo;
            int bbyte = ((brow << 7) + ((kk*4 + hi) << 4)) ^ ((brow & 7) << 4);
            bf16x8 bf = *(const bf16x8*)(Bw + bbyte);
            acc[nt] = __builtin_amdgcn_mfma_f32_16x16x32_bf16(afr[kk], bf, acc[nt], 0, 0, 0);
        }
    }
    #pragma unroll
    for (int nt = 0; nt < 4; ++nt) {
        int col = nt*16 + lo;
        float bb = b_red[col];
        #pragma unroll
        for (int r = 0; r < 4; ++r) {
            int row = wv*16 + hi*4 + r;
            int byte = ((row << 7) + (col << 1)) ^ ((row & 7) << 4);
            *(unsigned short*)(Rt + byte) = f2bf(fmaxf(acc[nt][r] + bb, 0.f));
        }
    }
    __syncthreads();

    #pragma unroll
    for (int i2 = 0; i2 < 2; ++i2) {
        int idx = i2*256 + t;
        int row = idx >> 3, ck = idx & 7;
        int r = i0 + row;
        if (r < n) {
            int byte = ((row << 7) + (ck << 4)) ^ ((row & 7) << 4);
            *(uint4*)&red32[(size_t)r*32 + ck*4] = *(const uint4*)(Rt + byte);
        }
    }
    {
        int half = t >> 5, c = t & 31;
        #pragma unroll
        for (int i2 = 0; i2 < 8; ++i2) {
            int p = i2*8 + half;
            int s0_ = segl[p];
            if (s0_ >= 0) {
                int byte = ((p << 7) + (c << 2)) ^ ((p & 7) << 4);
                unsigned int pk = *(const unsigned int*)(Rt + byte);
                atom_pk_bf16(&sums_pk[(size_t)s0_*32 + c], pk);
            }
        }
    }
    asm volatile("s_waitcnt vmcnt(0)" ::: "memory");
}

// k_pyramid: scales 1+2 from scale-0 (unconditional loads — latency-friendly).
__global__ __launch_bounds__(256) void k_pyramid(
    unsigned int* __restrict__ sums_pk, float* __restrict__ cnt)
{
    int t = threadIdx.x;
    int lane = t & 31;
    int cg = blockIdx.x * 8 + (t >> 5);

    float a0 = 0.f, a1 = 0.f, ca = 0.f;
    int outSeg = -1;

    if (cg < 65536) {                       // scale 1 (ps=4): 8 children
        int r1 = cg;
        int qz = r1 & 7, qy = (r1 >> 3) & 63, qx = (r1 >> 9) & 63, b = r1 >> 15;
        #pragma unroll
        for (int d = 0; d < 8; ++d) {
            int x2 = 2*qx + (d>>2), y2 = 2*qy + ((d>>1)&1), z2 = 2*qz + (d&1);
            int child = ((b*128 + x2)*128 + y2)*16 + z2;
            unsigned int v = sums_pk[(size_t)child*32 + lane];
            a0 += bf2f((unsigned short)(v & 0xffff));
            a1 += bf2f((unsigned short)(v >> 16));
            if (lane == 0) ca += cnt[child];
        }
        outSeg = SEG1 + r1;
    } else {                                // scale 2 (ps=6): <=27 children
        int r2 = cg - 65536;
        if (r2 < 22188) {
            int z6 = r2 % 6; int tmp = r2 / 6;
            int y6 = tmp % 43; tmp /= 43;
            int x6 = tmp % 43; int b = tmp / 43;
            for (int dx = 0; dx < 3; ++dx) {
                int x2 = 3*x6 + dx; if (x2 >= 128) break;
                for (int dy = 0; dy < 3; ++dy) {
                    int y2 = 3*y6 + dy; if (y2 >= 128) break;
                    for (int dz = 0; dz < 3; ++dz) {
                        int z2 = 3*z6 + dz; if (z2 >= 16) break;
                        int child = ((b*128 + x2)*128 + y2)*16 + z2;
                        unsigned int v = sums_pk[(size_t)child*32 + lane];
                        a0 += bf2f((unsigned short)(v & 0xffff));
                        a1 += bf2f((unsigned short)(v >> 16));
                        if (lane == 0) ca += cnt[child];
                    }
                }
            }
            outSeg = SEG2 + r2;
        }
    }

    if (outSeg >= 0) {
        unsigned int pk = (unsigned int)f2bf(a0) | ((unsigned int)f2bf(a1) << 16);
        sums_pk[(size_t)outSeg*32 + lane] = pk;
        if (lane == 0) cnt[outSeg] = ca;
    }
}

// k_pyr3: scale 3 (ps=8) from scale-1 children (exact 2x2x2 nesting).
__global__ __launch_bounds__(256) void k_pyr3(
    unsigned int* __restrict__ sums_pk, float* __restrict__ cnt)
{
    int t = threadIdx.x;
    int lane = t & 31;
    int r3 = blockIdx.x * 8 + (t >> 5);
    int z8 = r3 & 3, y8 = (r3 >> 2) & 31, x8 = (r3 >> 7) & 31, b = r3 >> 12;
    float a0 = 0.f, a1 = 0.f, ca = 0.f;
    #pragma unroll
    for (int d = 0; d < 8; ++d) {
        int qx = 2*x8 + (d>>2), qy = 2*y8 + ((d>>1)&1), qz = 2*z8 + (d&1);
        int child = SEG1 + ((b*64 + qx)*64 + qy)*8 + qz;
        unsigned int v = sums_pk[(size_t)child*32 + lane];
        a0 += bf2f((unsigned short)(v & 0xffff));
        a1 += bf2f((unsigned short)(v >> 16));
        if (lane == 0) ca += cnt[child];
    }
    unsigned int pk = (unsigned int)f2bf(a0) | ((unsigned int)f2bf(a1) << 16);
    sums_pk[(size_t)(SEG3 + r3)*32 + lane] = pk;
    if (lane == 0) cnt[SEG3 + r3] = ca;
}

// k2 via MFMA: A-fragments straight from global bf16 sums; inv applied in
// epilogue (scaling A row m scales D row m). att = relu(inv*(sums@W)+b).
__global__ __launch_bounds__(256) void k2_mfma(
    const unsigned int* __restrict__ sums_pk, const float* __restrict__ cnt,
    const char* __restrict__ wq, const float* __restrict__ b_pool,
    unsigned short* __restrict__ att)
{
    __shared__ uint4 Bs4[256];  // W_pool[j]^T bf16 swizzled, 4KB
    __shared__ float invs[64];
    char* Bs = (char*)Bs4;

    int t = threadIdx.x;
    int bid = blockIdx.x;
    int j, rel;
    if (bid < K2B0)      { j = 0; rel = bid; }
    else if (bid < K2B1) { j = 1; rel = bid - K2B0; }
    else if (bid < K2B2) { j = 2; rel = bid - K2B1; }
    else                 { j = 3; rel = bid - K2B2; }
    const int segStartT[4] = {0, SEG1, SEG2, SEG3};
    const int segEndT[4]   = {SEG1, SEG2, SEG3, SEGT};
    int s0 = segStartT[j] + rel * 64;
    int sEnd = segEndT[j];

    Bs4[t] = ((const uint4*)(wq + 8192 + j*4096))[t];
    if (t < 64) {
        int s = s0 + t;
        invs[t] = (s < sEnd) ? 1.f / fmaxf(cnt[s], 1.f) : 0.f;
    }
    __syncthreads();

    int lane = t & 63, wv = t >> 6;
    int hi = lane >> 4, lo = lane & 15;
    int arow = wv*16 + lo;
    int srow = s0 + arow;

    // A fragments direct from global: sums row srow (128B), bytes kk*64 + hi*16
    bf16x8 afr[2];
    #pragma unroll
    for (int kk = 0; kk < 2; ++kk) {
        uint4 v = {0u,0u,0u,0u};
        if (srow < sEnd)
            v = *(const uint4*)((const char*)sums_pk + (size_t)srow*128 + kk*64 + hi*16);
        afr[kk] = *(const bf16x8*)&v;
    }

    f32x4 acc[2];
    acc[0] = (f32x4){0.f,0.f,0.f,0.f};
    acc[1] = (f32x4){0.f,0.f,0.f,0.f};
    #pragma unroll
    for (int kk = 0; kk < 2; ++kk) {
        #pragma unroll
        for (int nt = 0; nt < 2; ++nt) {
            int brow = nt*16 + lo;
            int bbyte = ((brow << 7) + ((kk*4 + hi) << 4)) ^ ((brow & 7) << 4);
            bf16x8 bf = *(const bf16x8*)(Bs + bbyte);
            acc[nt] = __builtin_amdgcn_mfma_f32_16x16x32_bf16(afr[kk], bf, acc[nt], 0, 0, 0);
        }
    }
    #pragma unroll
    for (int nt = 0; nt < 2; ++nt) {
        int col = nt*16 + lo;
        float bp = b_pool[j*32 + col];
        #pragma unroll
        for (int r = 0; r < 4; ++r) {
            int row = wv*16 + hi*4 + r;
            int s = s0 + row;
            if (s < sEnd)
                att[(size_t)s*32 + col] = f2bf(fmaxf(acc[nt][r]*invs[row] + bp, 0.f));
        }
    }
}

// k3a via MFMA with fused shfl-ssum; As/Ws aliased; pre-swizzled weights.
__global__ __launch_bounds__(256) void k3a_mfma(
    const int* __restrict__ coords, const unsigned short* __restrict__ att,
    const char* __restrict__ wq, const float* __restrict__ b_att,
    unsigned short* __restrict__ sfeat, int n)
{
    __shared__ uint4 wcomb4[896];   // wz(2KB) + watt(8KB) + wot(4KB), 14KB
    __shared__ unsigned short sf[8192];  // 16KB
    __shared__ unsigned short AsWs[2048]; // 4KB
    __shared__ unsigned short Fz[2048];   // 4KB
    __shared__ int segl[64][4];
    char* wzp  = (char*)wcomb4;
    char* wattp = (char*)wcomb4 + 2048;
    char* wotp = (char*)wcomb4 + 10240;

    int t = threadIdx.x;
    int i0 = blockIdx.x * 64;
    if (t < 64) {
        int r = i0 + t; if (r >= n) r = n - 1;
        int sg[4]; seg4(coords[r*4], coords[r*4+1], coords[r*4+2], coords[r*4+3], sg);
        segl[t][0]=sg[0]; segl[t][1]=sg[1]; segl[t][2]=sg[2]; segl[t][3]=sg[3];
    }
    {
        const uint4* src = (const uint4*)(wq + 24576);
        for (int idx = t; idx < 896; idx += 256) wcomb4[idx] = src[idx];
    }
    __syncthreads();

    #pragma unroll
    for (int i = 0; i < 4; ++i) {
        int idx = i*256 + t;
        int p = idx >> 4, j = (idx >> 2) & 3, ck = idx & 3;
        int s = segl[p][j];
        uint4 v = *(const uint4*)(att + (size_t)s*32 + ck*8);
        int off = (j*64 + ck*16) ^ (((p>>2)&3) << 4);
        *(uint4*)((char*)sf + p*256 + off) = v;
        unsigned int w_[4] = {v.x, v.y, v.z, v.w};
        float f[8];
        #pragma unroll
        for (int q = 0; q < 4; ++q) {
            f[2*q]   = bf2f((unsigned short)(w_[q] & 0xffff));
            f[2*q+1] = bf2f((unsigned short)(w_[q] >> 16));
        }
        #pragma unroll
        for (int q = 0; q < 8; ++q) {
            f[q] += __shfl_xor(f[q], 4);
            f[q] += __shfl_xor(f[q], 8);
        }
        if (j == 0) {
            unsigned short u8[8];
            #pragma unroll
            for (int q = 0; q < 8; ++q) u8[q] = f2bf(f[q]);
            *(uint4*)((char*)AsWs + (ck*64 + p)*16) = *(const uint4*)u8;
        }
    }
    __syncthreads();

    int lane = t & 63, wv = t >> 6;
    int hi = lane >> 4, lo = lane & 15;
    int arow = wv*16 + lo;

    {
        bf16x8 af = *(const bf16x8*)((char*)AsWs + (hi*64 + arow)*16);
        f32x4 d0 = (f32x4){0.f,0.f,0.f,0.f}, d1 = (f32x4){0.f,0.f,0.f,0.f};
        bf16x8 b0 = *(const bf16x8*)(wzp + (hi*32 + lo)*16);
        bf16x8 b1 = *(const bf16x8*)(wzp + (hi*32 + 16 + lo)*16);
        d0 = __builtin_amdgcn_mfma_f32_16x16x32_bf16(af, b0, d0, 0,0,0);
        d1 = __builtin_amdgcn_mfma_f32_16x16x32_bf16(af, b1, d1, 0,0,0);
        #pragma unroll
        for (int r = 0; r < 4; ++r) {
            int row = wv*16 + hi*4 + r;
            int c0 = lo, c1 = 16 + lo;
            *(unsigned short*)((char*)Fz + ((c0>>3)*64 + row)*16 + (c0&7)*2) = f2bf(fmaxf(d0[r], 0.f));
            *(unsigned short*)((char*)Fz + ((c1>>3)*64 + row)*16 + (c1&7)*2) = f2bf(fmaxf(d1[r], 0.f));
        }
    }
    __syncthreads();
    {
        float wacc[2][4] = {{0.f,0.f,0.f,0.f},{0.f,0.f,0.f,0.f}};
        bf16x8 af = *(const bf16x8*)((char*)Fz + (hi*64 + arow)*16);
        #pragma unroll
        for (int j = 0; j < 4; ++j) {
            f32x4 d0 = (f32x4){0.f,0.f,0.f,0.f}, d1 = (f32x4){0.f,0.f,0.f,0.f};
            bf16x8 b0 = *(const bf16x8*)(wattp + j*2048 + (hi*32 + lo)*16);
            bf16x8 b1 = *(const bf16x8*)(wattp + j*2048 + (hi*32 + 16 + lo)*16);
            d0 = __builtin_amdgcn_mfma_f32_16x16x32_bf16(af, b0, d0, 0,0,0);
            d1 = __builtin_amdgcn_mfma_f32_16x16x32_bf16(af, b1, d1, 0,0,0);
            float ba0 = b_att[j*32 + lo], ba1 = b_att[j*32 + 16 + lo];
            #pragma unroll
            for (int r = 0; r < 4; ++r) {
                int row = wv*16 + hi*4 + r;
                float s0 = 1.f / (1.f + __expf(-(d0[r] + ba0)));
                float s1 = 1.f / (1.f + __expf(-(d1[r] + ba1)));
                float v0 = bf2f(*(const unsigned short*)((char*)sf + row*256 + ((j*64 + lo*2) ^ (hi<<4))));
                float v1 = bf2f(*(const unsigned short*)((char*)sf + row*256 + ((j*64 + (16+lo)*2) ^ (hi<<4))));
                wacc[0][r] += v0 * s0;
                wacc[1][r] += v1 * s1;
            }
        }
        __syncthreads();
        #pragma unroll
        for (int nt = 0; nt < 2; ++nt) {
            int col = nt*16 + lo;
            #pragma unroll
            for (int r = 0; r < 4; ++r) {
                int row = wv*16 + hi*4 + r;
                *(unsigned short*)((char*)AsWs + ((col>>3)*64 + row)*16 + (col&7)*2) = f2bf(wacc[nt][r]);
            }
        }
    }
    __syncthreads();
    {
        bf16x8 af = *(const bf16x8*)((char*)AsWs + (hi*64 + arow)*16);
        #pragma unroll
        for (int nt = 0; nt < 4; ++nt) {
            f32x4 d = (f32x4){0.f,0.f,0.f,0.f};
            bf16x8 bf = *(const bf16x8*)(wotp + (hi*64 + nt*16 + lo)*16);
            d = __builtin_amdgcn_mfma_f32_16x16x32_bf16(af, bf, d, 0,0,0);
            int col = nt*16 + lo;
            #pragma unroll
            for (int r = 0; r < 4; ++r) {
                int row = i0 + wv*16 + hi*4 + r;
                if (row < n) sfeat[(size_t)row*64 + col] = f2bf(d[r]);
            }
        }
    }
}

// k3b via MFMA: A-fragments ([red|sfeat] gathered rows) straight from global.
__global__ __launch_bounds__(256) void k3b_mfma(
    const int* __restrict__ cinv,
    const unsigned short* __restrict__ red, const unsigned short* __restrict__ sfeat,
    const char* __restrict__ wq, const float* __restrict__ b_l2,
    float* __restrict__ out, int n)
{
    __shared__ uint4 wl4[1536];   // wl1 16KB + wl2 8KB
    __shared__ uint4 hs4[512];    // 8KB
    __shared__ int rl[64];
    char* wl1 = (char*)wl4;
    char* wl2 = (char*)wl4 + 16384;
    char* hs  = (char*)hs4;

    int t = threadIdx.x;
    int i0 = blockIdx.x * 64;
    if (t < 64) { int i = i0 + t; rl[t] = cinv[(i < n) ? i : (n-1)]; }

    {
        const uint4* src = (const uint4*)(wq + 38912);
        for (int idx = t; idx < 1536; idx += 256) wl4[idx] = src[idx];
    }
    __syncthreads();

    int lane = t & 63, wv = t >> 6;
    int hi = lane >> 4, lo = lane & 15;
    int arow = wv*16 + lo;
    int grow = rl[arow];

    // layer 1: h = relu(of @ W_l1), K=128; of row = [red[grow] | sfeat[grow]]
    f32x4 acc[4];
    #pragma unroll
    for (int nt = 0; nt < 4; ++nt) acc[nt] = (f32x4){0.f,0.f,0.f,0.f};
    #pragma unroll
    for (int kk = 0; kk < 4; ++kk) {
        int k0 = kk*32 + hi*8;     // ushort index within 128-wide of-row
        const unsigned short* src = (k0 < 64) ? (red + (size_t)grow*64 + k0)
                                              : (sfeat + (size_t)grow*64 + (k0 - 64));
        bf16x8 af = *(const bf16x8*)src;
        #pragma unroll
        for (int nt = 0; nt < 4; ++nt) {
            int brow = nt*16 + lo;
            int bbyte = ((brow << 8) + ((kk*4 + hi) << 4)) ^ ((brow & 7) << 4);
            bf16x8 bf = *(const bf16x8*)(wl1 + bbyte);
            acc[nt] = __builtin_amdgcn_mfma_f32_16x16x32_bf16(af, bf, acc[nt], 0, 0, 0);
        }
    }
    #pragma unroll
    for (int nt = 0; nt < 4; ++nt) {
        #pragma unroll
        for (int r = 0; r < 4; ++r) {
            int row = wv*16 + hi*4 + r;
            int col = nt*16 + lo;
            int byte = ((row << 7) + (col << 1)) ^ ((row & 7) << 4);
            *(unsigned short*)(hs + byte) = f2bf(fmaxf(acc[nt][r], 0.f));
        }
    }
    __syncthreads();

    f32x4 acc2[4];
    #pragma unroll
    for (int nt = 0; nt < 4; ++nt) acc2[nt] = (f32x4){0.f,0.f,0.f,0.f};
    #pragma unroll
    for (int kk = 0; kk < 2; ++kk) {
        int abyte = ((arow << 7) + ((kk*4 + hi) << 4)) ^ ((arow & 7) << 4);
        bf16x8 af = *(const bf16x8*)(hs + abyte);
        #pragma unroll
        for (int nt = 0; nt < 4; ++nt) {
            int brow = nt*16 + lo;
            int bbyte = ((brow << 7) + ((kk*4 + hi) << 4)) ^ ((brow & 7) << 4);
            bf16x8 bf = *(const bf16x8*)(wl2 + bbyte);
            acc2[nt] = __builtin_amdgcn_mfma_f32_16x16x32_bf16(af, bf, acc2[nt], 0, 0, 0);
        }
    }
    #pragma unroll
    for (int nt = 0; nt < 4; ++nt) {
        int col = nt*16 + lo;
        float bl = b_l2[col];
        #pragma unroll
        for (int r = 0; r < 4; ++r) {
            int row = i0 + wv*16 + hi*4 + r;
            if (row < n) out[(size_t)row*64 + col] = acc2[nt][r] + bl;
        }
    }
}

extern "C" void kernel_launch(void* const* d_in, const int* in_sizes, int n_in,
                              void* d_out, int out_size, void* d_ws, size_t ws_size,
                              hipStream_t stream) {
    const float* x      = (const float*)d_in[0];
    const int*   coords = (const int*)  d_in[1];
    const int*   cinv   = (const int*)  d_in[2];
    const float* W_red  = (const float*)d_in[3];
    const float* b_red  = (const float*)d_in[4];
    const float* W_pool = (const float*)d_in[5];
    const float* b_pool = (const float*)d_in[6];
    const float* W_att  = (const float*)d_in[7];
    const float* b_att  = (const float*)d_in[8];
    const float* W_z    = (const float*)d_in[9];
    const float* W_out  = (const float*)d_in[10];
    const float* W_l1   = (const float*)d_in[11];
    const float* W_l2   = (const float*)d_in[12];
    const float* b_l2   = (const float*)d_in[13];
    float* out = (float*)d_out;
    int n = in_sizes[0] / 64;

    char* wsb = (char*)d_ws;
    unsigned int*   red32   = (unsigned int*)(wsb);
    unsigned short* red     = (unsigned short*)(wsb);
    unsigned int*   sums_pk = (unsigned int*)(wsb + SUMS_OFF);
    float*          cnt     = (float*)(wsb + CNT_OFF);
    unsigned short* att     = (unsigned short*)(wsb + ATT_OFF);
    char*           wq      = wsb + WQ_OFF;
    unsigned short* sfeat   = (unsigned short*)(wsb + SUMS_OFF);  // alias: sums dead after k2

    k0_wprep<<<124, 256, 0, stream>>>(W_red, W_pool, W_z, W_att, W_out, W_l1, W_l2, wq);
    hipMemsetAsync(sums_pk, 0, (size_t)SEG1 * 128ull, stream);
    hipMemsetAsync(cnt, 0, (size_t)SEG1 * 4ull, stream);

    k1_mfma<<<(n + 63) / 64, 256, 0, stream>>>(x, coords, wq, b_red, red32, sums_pk, cnt, n);
    k_pyramid<<<PYRB12, 256, 0, stream>>>(sums_pk, cnt);
    k_pyr3<<<1024, 256, 0, stream>>>(sums_pk, cnt);
    k2_mfma<<<K2BT, 256, 0, stream>>>(sums_pk, cnt, wq, b_pool, att);
    k3a_mfma<<<(n + 63) / 64, 256, 0, stream>>>(coords, att, wq, b_att, sfeat, n);
    k3b_mfma<<<(n + 63) / 64, 256, 0, stream>>>(cinv, red, sfeat, wq, b_l2, out, n);
}

// Round 15
// 207.430 us; speedup vs baseline: 1.2410x; 1.0500x over previous
//
#include <hip/hip_runtime.h>
#include <hip/hip_bf16.h>

// Segment counts per scale: ps=2:(128,128,16) ps=4:(64,64,8) ps=6:(43,43,6) ps=8:(32,32,4), B=2
#define SEG1 524288
#define SEG2 589824
#define SEG3 612012
#define SEGT 620204

// k2 block mapping (4 tiles of 64 segs per block): blocks/scale = {2048,256,87,32}
#define K2B0 2048
#define K2B1 2304
#define K2B2 2391
#define K2BT 2423

#define PYRB12 10968

// ws layout (BYTES):
//   red_bf16   @ 0           : 32,000,000 B
//   sums_bf16  @ 32,000,000  : 79,386,112 B (SEGT*64 bf16 packed)
//   cnt        @ 111,386,112 : 2,480,816 B
//   att_bf16   @ 113,866,928 : 39,693,056 B (end 153,559,984)
//   wq (pre-swizzled bf16 weights) @ 153,560,064 : 63,488 B
//   sfeat_bf16 aliases sums start (sums dead after k2)
#define SUMS_OFF 32000000ull
#define CNT_OFF  111386112ull
#define ATT_OFF  113866928ull
#define WQ_OFF   153560064ull
// wq sections: k1Bw 0 (8192) | k2Bs 8192 (16384, 4096/j) | wz 24576 (2048)
//   | watt 26624 (8192) | wot 34816 (4096) | wl1 38912 (16384) | wl2 55296 (8192)

typedef __attribute__((ext_vector_type(8))) __bf16 bf16x8;
typedef __attribute__((ext_vector_type(4))) float  f32x4;

__device__ __forceinline__ float bf2f(unsigned short u) {
    union { unsigned int i; float f; } v; v.i = ((unsigned int)u) << 16; return v.f;
}
__device__ __forceinline__ unsigned short f2bf(float f) {
    union { float f; unsigned int i; } v; v.f = f;
    unsigned int r = v.i + 0x7FFF + ((v.i >> 16) & 1);
    return (unsigned short)(r >> 16);
}
__device__ __forceinline__ void atom_pk_bf16(unsigned int* addr, unsigned int pk) {
    asm volatile("global_atomic_pk_add_bf16 %0, %1, off" :: "v"(addr), "v"(pk) : "memory");
}

__device__ __forceinline__ int seg0_of(int b, int cx, int cy, int cz) {
    return ((b*128 + (cx>>1))*128 + (cy>>1))*16 + (cz>>1);
}
__device__ __forceinline__ void seg4(int b, int cx, int cy, int cz, int* s) {
    s[0] =        ((b*128 + (cx>>1))*128 + (cy>>1))*16 + (cz>>1);
    s[1] = SEG1 + ((b*64  + (cx>>2))*64  + (cy>>2))*8  + (cz>>2);
    s[2] = SEG2 + ((b*43  + (cx/6 ))*43  + (cy/6 ))*6  + (cz/6 );
    s[3] = SEG3 + ((b*32  + (cx>>3))*32  + (cy>>3))*4  + (cz>>3);
}

// k0: convert + pre-swizzle all weights into wq.
__global__ __launch_bounds__(256) void k0_wprep(
    const float* __restrict__ W_red, const float* __restrict__ W_pool,
    const float* __restrict__ W_z, const float* __restrict__ W_att,
    const float* __restrict__ W_out, const float* __restrict__ W_l1,
    const float* __restrict__ W_l2, char* __restrict__ wq)
{
    int g = blockIdx.x*256 + threadIdx.x;
    if (g < 4096) {
        int idx = g; int k = idx>>6, c = idx&63;
        int byte = (((c<<7)+(k<<1)) ^ ((c&7)<<4));
        *(unsigned short*)(wq + byte) = f2bf(W_red[idx]);
    } else if (g < 12288) {
        int idx = g - 4096; int j = idx>>11, r2 = idx&2047, k = r2>>5, c = r2&31;
        int byte = j*4096 + (((c<<7)+(k<<1)) ^ ((c&7)<<4));
        *(unsigned short*)(wq + 8192 + byte) = f2bf(W_pool[idx]);
    } else if (g < 13312) {
        int idx = g - 12288; int k = idx>>5, c = idx&31;
        *(unsigned short*)(wq + 24576 + ((k>>3)*32+c)*16 + (k&7)*2) = f2bf(W_z[idx]);
    } else if (g < 17408) {
        int idx = g - 13312; int j = idx>>10, rem = idx&1023, k = rem>>5, c = rem&31;
        *(unsigned short*)(wq + 26624 + j*2048 + ((k>>3)*32+c)*16 + (k&7)*2) = f2bf(W_att[idx]);
    } else if (g < 19456) {
        int idx = g - 17408; int k = idx>>6, c = idx&63;
        *(unsigned short*)(wq + 34816 + ((k>>3)*64+c)*16 + (k&7)*2) = f2bf(W_out[idx]);
    } else if (g < 27648) {
        int idx = g - 19456; int k = idx>>6, c = idx&63;
        int byte = (((c<<8)+(k<<1)) ^ ((c&7)<<4));
        *(unsigned short*)(wq + 38912 + byte) = f2bf(W_l1[idx]);
    } else if (g < 31744) {
        int idx = g - 27648; int k = idx>>6, c = idx&63;
        int byte = (((c<<7)+(k<<1)) ^ ((c&7)<<4));
        *(unsigned short*)(wq + 55296 + byte) = f2bf(W_l2[idx]);
    }
}

// k1 via MFMA: A-fragments straight from global x (fp32->bf16 in regs);
// red = relu(x@W_red+b) bf16; pk-bf16 atomic scatter to scale-0 only.
__global__ __launch_bounds__(256) void k1_mfma(
    const float* __restrict__ x, const int* __restrict__ coords,
    const char* __restrict__ wq, const float* __restrict__ b_red,
    unsigned int* __restrict__ red32, unsigned int* __restrict__ sums_pk,
    float* __restrict__ cnt, int n)
{
    __shared__ uint4 Bw4[512];   // W_red^T bf16 swizzled, 8KB
    __shared__ uint4 Rt4[512];   // red bf16 swizzled, 8KB
    __shared__ int segl[64];
    char* Bw = (char*)Bw4; char* Rt = (char*)Rt4;

    int t = threadIdx.x;
    int i0 = blockIdx.x * 64;

    if (t < 64) {
        int r = i0 + t;
        if (r < n) {
            int4 cv = *(const int4*)&coords[(size_t)r*4];
            int s0 = seg0_of(cv.x, cv.y, cv.z, cv.w);
            segl[t] = s0;
            unsafeAtomicAdd(&cnt[s0], 1.f);
        } else segl[t] = -1;
    }
    {
        const uint4* src = (const uint4*)wq;
        Bw4[t] = src[t];
        Bw4[t + 256] = src[t + 256];
    }
    __syncthreads();

    int lane = t & 63, wv = t >> 6;
    int hi = lane >> 4, lo = lane & 15;
    int arow = wv*16 + lo;
    int grow = i0 + arow;

    bf16x8 afr[2];
    #pragma unroll
    for (int kk = 0; kk < 2; ++kk) {
        unsigned short u[8];
        if (grow < n) {
            const float* xp = x + (size_t)grow*64 + kk*32 + hi*8;
            float4 v0 = *(const float4*)xp;
            float4 v1 = *(const float4*)(xp + 4);
            u[0]=f2bf(v0.x); u[1]=f2bf(v0.y); u[2]=f2bf(v0.z); u[3]=f2bf(v0.w);
            u[4]=f2bf(v1.x); u[5]=f2bf(v1.y); u[6]=f2bf(v1.z); u[7]=f2bf(v1.w);
        } else {
            #pragma unroll
            for (int q = 0; q < 8; ++q) u[q] = 0;
        }
        afr[kk] = *(const bf16x8*)u;
    }

    f32x4 acc[4];
    #pragma unroll
    for (int nt = 0; nt < 4; ++nt) acc[nt] = (f32x4){0.f,0.f,0.f,0.f};
    #pragma unroll
    for (int kk = 0; kk < 2; ++kk) {
        #pragma unroll
        for (int nt = 0; nt < 4; ++nt) {
            int brow = nt*16 + lo;
            int bbyte = ((brow << 7) + ((kk*4 + hi) << 4)) ^ ((brow & 7) << 4);
            bf16x8 bf = *(const bf16x8*)(Bw + bbyte);
            acc[nt] = __builtin_amdgcn_mfma_f32_16x16x32_bf16(afr[kk], bf, acc[nt], 0, 0, 0);
        }
    }
    #pragma unroll
    for (int nt = 0; nt < 4; ++nt) {
        int col = nt*16 + lo;
        float bb = b_red[col];
        #pragma unroll
        for (int r = 0; r < 4; ++r) {
            int row = wv*16 + hi*4 + r;
            int byte = ((row << 7) + (col << 1)) ^ ((row & 7) << 4);
            *(unsigned short*)(Rt + byte) = f2bf(fmaxf(acc[nt][r] + bb, 0.f));
        }
    }
    __syncthreads();

    #pragma unroll
    for (int i2 = 0; i2 < 2; ++i2) {
        int idx = i2*256 + t;
        int row = idx >> 3, ck = idx & 7;
        int r = i0 + row;
        if (r < n) {
            int byte = ((row << 7) + (ck << 4)) ^ ((row & 7) << 4);
            *(uint4*)&red32[(size_t)r*32 + ck*4] = *(const uint4*)(Rt + byte);
        }
    }
    {
        int half = t >> 5, c = t & 31;
        #pragma unroll
        for (int i2 = 0; i2 < 8; ++i2) {
            int p = i2*8 + half;
            int s0_ = segl[p];
            if (s0_ >= 0) {
                int byte = ((p << 7) + (c << 2)) ^ ((p & 7) << 4);
                unsigned int pk = *(const unsigned int*)(Rt + byte);
                atom_pk_bf16(&sums_pk[(size_t)s0_*32 + c], pk);
            }
        }
    }
    // no trailing vmcnt wait: pk-atomics are fire-and-forget; dispatch-completion fences them
}

// k_pyramid: scales 1+2 from scale-0 (unconditional loads — latency-friendly).
__global__ __launch_bounds__(256) void k_pyramid(
    unsigned int* __restrict__ sums_pk, float* __restrict__ cnt)
{
    int t = threadIdx.x;
    int lane = t & 31;
    int cg = blockIdx.x * 8 + (t >> 5);

    float a0 = 0.f, a1 = 0.f, ca = 0.f;
    int outSeg = -1;

    if (cg < 65536) {                       // scale 1 (ps=4): 8 children
        int r1 = cg;
        int qz = r1 & 7, qy = (r1 >> 3) & 63, qx = (r1 >> 9) & 63, b = r1 >> 15;
        #pragma unroll
        for (int d = 0; d < 8; ++d) {
            int x2 = 2*qx + (d>>2), y2 = 2*qy + ((d>>1)&1), z2 = 2*qz + (d&1);
            int child = ((b*128 + x2)*128 + y2)*16 + z2;
            unsigned int v = sums_pk[(size_t)child*32 + lane];
            a0 += bf2f((unsigned short)(v & 0xffff));
            a1 += bf2f((unsigned short)(v >> 16));
            if (lane == 0) ca += cnt[child];
        }
        outSeg = SEG1 + r1;
    } else {                                // scale 2 (ps=6): <=27 children
        int r2 = cg - 65536;
        if (r2 < 22188) {
            int z6 = r2 % 6; int tmp = r2 / 6;
            int y6 = tmp % 43; tmp /= 43;
            int x6 = tmp % 43; int b = tmp / 43;
            for (int dx = 0; dx < 3; ++dx) {
                int x2 = 3*x6 + dx; if (x2 >= 128) break;
                for (int dy = 0; dy < 3; ++dy) {
                    int y2 = 3*y6 + dy; if (y2 >= 128) break;
                    for (int dz = 0; dz < 3; ++dz) {
                        int z2 = 3*z6 + dz; if (z2 >= 16) break;
                        int child = ((b*128 + x2)*128 + y2)*16 + z2;
                        unsigned int v = sums_pk[(size_t)child*32 + lane];
                        a0 += bf2f((unsigned short)(v & 0xffff));
                        a1 += bf2f((unsigned short)(v >> 16));
                        if (lane == 0) ca += cnt[child];
                    }
                }
            }
            outSeg = SEG2 + r2;
        }
    }

    if (outSeg >= 0) {
        unsigned int pk = (unsigned int)f2bf(a0) | ((unsigned int)f2bf(a1) << 16);
        sums_pk[(size_t)outSeg*32 + lane] = pk;
        if (lane == 0) cnt[outSeg] = ca;
    }
}

// k_pyr3: scale 3 (ps=8) from scale-1 children (exact 2x2x2 nesting).
__global__ __launch_bounds__(256) void k_pyr3(
    unsigned int* __restrict__ sums_pk, float* __restrict__ cnt)
{
    int t = threadIdx.x;
    int lane = t & 31;
    int r3 = blockIdx.x * 8 + (t >> 5);
    int z8 = r3 & 3, y8 = (r3 >> 2) & 31, x8 = (r3 >> 7) & 31, b = r3 >> 12;
    float a0 = 0.f, a1 = 0.f, ca = 0.f;
    #pragma unroll
    for (int d = 0; d < 8; ++d) {
        int qx = 2*x8 + (d>>2), qy = 2*y8 + ((d>>1)&1), qz = 2*z8 + (d&1);
        int child = SEG1 + ((b*64 + qx)*64 + qy)*8 + qz;
        unsigned int v = sums_pk[(size_t)child*32 + lane];
        a0 += bf2f((unsigned short)(v & 0xffff));
        a1 += bf2f((unsigned short)(v >> 16));
        if (lane == 0) ca += cnt[child];
    }
    unsigned int pk = (unsigned int)f2bf(a0) | ((unsigned int)f2bf(a1) << 16);
    sums_pk[(size_t)(SEG3 + r3)*32 + lane] = pk;
    if (lane == 0) cnt[SEG3 + r3] = ca;
}

// k2 via MFMA: 4 tiles of 64 segs per block; A-fragments straight from global
// bf16 sums; inv applied in epilogue. att = relu(inv*(sums@W)+b).
__global__ __launch_bounds__(256) void k2_mfma(
    const unsigned int* __restrict__ sums_pk, const float* __restrict__ cnt,
    const char* __restrict__ wq, const float* __restrict__ b_pool,
    unsigned short* __restrict__ att)
{
    __shared__ uint4 Bs4[256];   // W_pool[j]^T bf16 swizzled, 4KB
    __shared__ float invs[256];
    char* Bs = (char*)Bs4;

    int t = threadIdx.x;
    int bid = blockIdx.x;
    int j, rel;
    if (bid < K2B0)      { j = 0; rel = bid; }
    else if (bid < K2B1) { j = 1; rel = bid - K2B0; }
    else if (bid < K2B2) { j = 2; rel = bid - K2B1; }
    else                 { j = 3; rel = bid - K2B2; }
    const int segStartT[4] = {0, SEG1, SEG2, SEG3};
    const int segEndT[4]   = {SEG1, SEG2, SEG3, SEGT};
    int s0 = segStartT[j] + rel * 256;
    int sEnd = segEndT[j];

    Bs4[t] = ((const uint4*)(wq + 8192 + j*4096))[t];
    {
        int s = s0 + t;
        invs[t] = (s < sEnd) ? 1.f / fmaxf(cnt[s], 1.f) : 0.f;
    }
    __syncthreads();

    int lane = t & 63, wv = t >> 6;
    int hi = lane >> 4, lo = lane & 15;
    int arow = wv*16 + lo;
    float bp0 = b_pool[j*32 + lo];
    float bp1 = b_pool[j*32 + 16 + lo];

    #pragma unroll
    for (int T = 0; T < 4; ++T) {
        int ts0 = s0 + T*64;
        int srow = ts0 + arow;

        bf16x8 afr[2];
        #pragma unroll
        for (int kk = 0; kk < 2; ++kk) {
            uint4 v = {0u,0u,0u,0u};
            if (srow < sEnd)
                v = *(const uint4*)((const char*)sums_pk + (size_t)srow*128 + kk*64 + hi*16);
            afr[kk] = *(const bf16x8*)&v;
        }

        f32x4 acc[2];
        acc[0] = (f32x4){0.f,0.f,0.f,0.f};
        acc[1] = (f32x4){0.f,0.f,0.f,0.f};
        #pragma unroll
        for (int kk = 0; kk < 2; ++kk) {
            #pragma unroll
            for (int nt = 0; nt < 2; ++nt) {
                int brow = nt*16 + lo;
                int bbyte = ((brow << 7) + ((kk*4 + hi) << 4)) ^ ((brow & 7) << 4);
                bf16x8 bf = *(const bf16x8*)(Bs + bbyte);
                acc[nt] = __builtin_amdgcn_mfma_f32_16x16x32_bf16(afr[kk], bf, acc[nt], 0, 0, 0);
            }
        }
        #pragma unroll
        for (int nt = 0; nt < 2; ++nt) {
            int col = nt*16 + lo;
            float bp = nt ? bp1 : bp0;
            #pragma unroll
            for (int r = 0; r < 4; ++r) {
                int row = T*64 + wv*16 + hi*4 + r;
                int s = s0 + row;
                if (s < sEnd)
                    att[(size_t)s*32 + col] = f2bf(fmaxf(acc[nt][r]*invs[row] + bp, 0.f));
            }
        }
    }
}

// k3a via MFMA with fused shfl-ssum; As/Ws aliased; pre-swizzled weights.
__global__ __launch_bounds__(256) void k3a_mfma(
    const int* __restrict__ coords, const unsigned short* __restrict__ att,
    const char* __restrict__ wq, const float* __restrict__ b_att,
    unsigned short* __restrict__ sfeat, int n)
{
    __shared__ uint4 wcomb4[896];   // wz(2KB) + watt(8KB) + wot(4KB), 14KB
    __shared__ unsigned short sf[8192];  // 16KB
    __shared__ unsigned short AsWs[2048]; // 4KB
    __shared__ unsigned short Fz[2048];   // 4KB
    __shared__ int segl[64][4];
    char* wzp  = (char*)wcomb4;
    char* wattp = (char*)wcomb4 + 2048;
    char* wotp = (char*)wcomb4 + 10240;

    int t = threadIdx.x;
    int i0 = blockIdx.x * 64;
    if (t < 64) {
        int r = i0 + t; if (r >= n) r = n - 1;
        int sg[4]; seg4(coords[r*4], coords[r*4+1], coords[r*4+2], coords[r*4+3], sg);
        segl[t][0]=sg[0]; segl[t][1]=sg[1]; segl[t][2]=sg[2]; segl[t][3]=sg[3];
    }
    {
        const uint4* src = (const uint4*)(wq + 24576);
        for (int idx = t; idx < 896; idx += 256) wcomb4[idx] = src[idx];
    }
    __syncthreads();

    #pragma unroll
    for (int i = 0; i < 4; ++i) {
        int idx = i*256 + t;
        int p = idx >> 4, j = (idx >> 2) & 3, ck = idx & 3;
        int s = segl[p][j];
        uint4 v = *(const uint4*)(att + (size_t)s*32 + ck*8);
        int off = (j*64 + ck*16) ^ (((p>>2)&3) << 4);
        *(uint4*)((char*)sf + p*256 + off) = v;
        unsigned int w_[4] = {v.x, v.y, v.z, v.w};
        float f[8];
        #pragma unroll
        for (int q = 0; q < 4; ++q) {
            f[2*q]   = bf2f((unsigned short)(w_[q] & 0xffff));
            f[2*q+1] = bf2f((unsigned short)(w_[q] >> 16));
        }
        #pragma unroll
        for (int q = 0; q < 8; ++q) {
            f[q] += __shfl_xor(f[q], 4);
            f[q] += __shfl_xor(f[q], 8);
        }
        if (j == 0) {
            unsigned short u8[8];
            #pragma unroll
            for (int q = 0; q < 8; ++q) u8[q] = f2bf(f[q]);
            *(uint4*)((char*)AsWs + (ck*64 + p)*16) = *(const uint4*)u8;
        }
    }
    __syncthreads();

    int lane = t & 63, wv = t >> 6;
    int hi = lane >> 4, lo = lane & 15;
    int arow = wv*16 + lo;

    {
        bf16x8 af = *(const bf16x8*)((char*)AsWs + (hi*64 + arow)*16);
        f32x4 d0 = (f32x4){0.f,0.f,0.f,0.f}, d1 = (f32x4){0.f,0.f,0.f,0.f};
        bf16x8 b0 = *(const bf16x8*)(wzp + (hi*32 + lo)*16);
        bf16x8 b1 = *(const bf16x8*)(wzp + (hi*32 + 16 + lo)*16);
        d0 = __builtin_amdgcn_mfma_f32_16x16x32_bf16(af, b0, d0, 0,0,0);
        d1 = __builtin_amdgcn_mfma_f32_16x16x32_bf16(af, b1, d1, 0,0,0);
        #pragma unroll
        for (int r = 0; r < 4; ++r) {
            int row = wv*16 + hi*4 + r;
            int c0 = lo, c1 = 16 + lo;
            *(unsigned short*)((char*)Fz + ((c0>>3)*64 + row)*16 + (c0&7)*2) = f2bf(fmaxf(d0[r], 0.f));
            *(unsigned short*)((char*)Fz + ((c1>>3)*64 + row)*16 + (c1&7)*2) = f2bf(fmaxf(d1[r], 0.f));
        }
    }
    __syncthreads();
    {
        float wacc[2][4] = {{0.f,0.f,0.f,0.f},{0.f,0.f,0.f,0.f}};
        bf16x8 af = *(const bf16x8*)((char*)Fz + (hi*64 + arow)*16);
        #pragma unroll
        for (int j = 0; j < 4; ++j) {
            f32x4 d0 = (f32x4){0.f,0.f,0.f,0.f}, d1 = (f32x4){0.f,0.f,0.f,0.f};
            bf16x8 b0 = *(const bf16x8*)(wattp + j*2048 + (hi*32 + lo)*16);
            bf16x8 b1 = *(const bf16x8*)(wattp + j*2048 + (hi*32 + 16 + lo)*16);
            d0 = __builtin_amdgcn_mfma_f32_16x16x32_bf16(af, b0, d0, 0,0,0);
            d1 = __builtin_amdgcn_mfma_f32_16x16x32_bf16(af, b1, d1, 0,0,0);
            float ba0 = b_att[j*32 + lo], ba1 = b_att[j*32 + 16 + lo];
            #pragma unroll
            for (int r = 0; r < 4; ++r) {
                int row = wv*16 + hi*4 + r;
                float s0 = 1.f / (1.f + __expf(-(d0[r] + ba0)));
                float s1 = 1.f / (1.f + __expf(-(d1[r] + ba1)));
                float v0 = bf2f(*(const unsigned short*)((char*)sf + row*256 + ((j*64 + lo*2) ^ (hi<<4))));
                float v1 = bf2f(*(const unsigned short*)((char*)sf + row*256 + ((j*64 + (16+lo)*2) ^ (hi<<4))));
                wacc[0][r] += v0 * s0;
                wacc[1][r] += v1 * s1;
            }
        }
        __syncthreads();
        #pragma unroll
        for (int nt = 0; nt < 2; ++nt) {
            int col = nt*16 + lo;
            #pragma unroll
            for (int r = 0; r < 4; ++r) {
                int row = wv*16 + hi*4 + r;
                *(unsigned short*)((char*)AsWs + ((col>>3)*64 + row)*16 + (col&7)*2) = f2bf(wacc[nt][r]);
            }
        }
    }
    __syncthreads();
    {
        bf16x8 af = *(const bf16x8*)((char*)AsWs + (hi*64 + arow)*16);
        #pragma unroll
        for (int nt = 0; nt < 4; ++nt) {
            f32x4 d = (f32x4){0.f,0.f,0.f,0.f};
            bf16x8 bf = *(const bf16x8*)(wotp + (hi*64 + nt*16 + lo)*16);
            d = __builtin_amdgcn_mfma_f32_16x16x32_bf16(af, bf, d, 0,0,0);
            int col = nt*16 + lo;
            #pragma unroll
            for (int r = 0; r < 4; ++r) {
                int row = i0 + wv*16 + hi*4 + r;
                if (row < n) sfeat[(size_t)row*64 + col] = f2bf(d[r]);
            }
        }
    }
}

// k3b via MFMA: 2 row-tiles per block; A-fragments straight from global.
__global__ __launch_bounds__(256) void k3b_mfma(
    const int* __restrict__ cinv,
    const unsigned short* __restrict__ red, const unsigned short* __restrict__ sfeat,
    const char* __restrict__ wq, const float* __restrict__ b_l2,
    float* __restrict__ out, int n)
{
    __shared__ uint4 wl4[1536];   // wl1 16KB + wl2 8KB
    __shared__ uint4 hs4[512];    // 8KB
    __shared__ int rl[128];
    char* wl1 = (char*)wl4;
    char* wl2 = (char*)wl4 + 16384;
    char* hs  = (char*)hs4;

    int t = threadIdx.x;
    int i0 = blockIdx.x * 128;
    if (t < 128) { int i = i0 + t; rl[t] = cinv[(i < n) ? i : (n-1)]; }

    {
        const uint4* src = (const uint4*)(wq + 38912);
        for (int idx = t; idx < 1536; idx += 256) wl4[idx] = src[idx];
    }
    __syncthreads();

    int lane = t & 63, wv = t >> 6;
    int hi = lane >> 4, lo = lane & 15;
    int arow = wv*16 + lo;

    #pragma unroll
    for (int T = 0; T < 2; ++T) {
        int grow = rl[T*64 + arow];

        // layer 1: h = relu(of @ W_l1), K=128; of row = [red[grow] | sfeat[grow]]
        f32x4 acc[4];
        #pragma unroll
        for (int nt = 0; nt < 4; ++nt) acc[nt] = (f32x4){0.f,0.f,0.f,0.f};
        #pragma unroll
        for (int kk = 0; kk < 4; ++kk) {
            int k0 = kk*32 + hi*8;
            const unsigned short* src = (k0 < 64) ? (red + (size_t)grow*64 + k0)
                                                  : (sfeat + (size_t)grow*64 + (k0 - 64));
            bf16x8 af = *(const bf16x8*)src;
            #pragma unroll
            for (int nt = 0; nt < 4; ++nt) {
                int brow = nt*16 + lo;
                int bbyte = ((brow << 8) + ((kk*4 + hi) << 4)) ^ ((brow & 7) << 4);
                bf16x8 bf = *(const bf16x8*)(wl1 + bbyte);
                acc[nt] = __builtin_amdgcn_mfma_f32_16x16x32_bf16(af, bf, acc[nt], 0, 0, 0);
            }
        }
        #pragma unroll
        for (int nt = 0; nt < 4; ++nt) {
            #pragma unroll
            for (int r = 0; r < 4; ++r) {
                int row = wv*16 + hi*4 + r;
                int col = nt*16 + lo;
                int byte = ((row << 7) + (col << 1)) ^ ((row & 7) << 4);
                *(unsigned short*)(hs + byte) = f2bf(fmaxf(acc[nt][r], 0.f));
            }
        }
        __syncthreads();

        // layer 2: out = h @ W_l2 + b_l2
        f32x4 acc2[4];
        #pragma unroll
        for (int nt = 0; nt < 4; ++nt) acc2[nt] = (f32x4){0.f,0.f,0.f,0.f};
        #pragma unroll
        for (int kk = 0; kk < 2; ++kk) {
            int abyte = ((arow << 7) + ((kk*4 + hi) << 4)) ^ ((arow & 7) << 4);
            bf16x8 af = *(const bf16x8*)(hs + abyte);
            #pragma unroll
            for (int nt = 0; nt < 4; ++nt) {
                int brow = nt*16 + lo;
                int bbyte = ((brow << 7) + ((kk*4 + hi) << 4)) ^ ((brow & 7) << 4);
                bf16x8 bf = *(const bf16x8*)(wl2 + bbyte);
                acc2[nt] = __builtin_amdgcn_mfma_f32_16x16x32_bf16(af, bf, acc2[nt], 0, 0, 0);
            }
        }
        #pragma unroll
        for (int nt = 0; nt < 4; ++nt) {
            int col = nt*16 + lo;
            float bl = b_l2[col];
            #pragma unroll
            for (int r = 0; r < 4; ++r) {
                int row = i0 + T*64 + wv*16 + hi*4 + r;
                if (row < n) out[(size_t)row*64 + col] = acc2[nt][r] + bl;
            }
        }
        __syncthreads();   // hs reused by next tile
    }
}

extern "C" void kernel_launch(void* const* d_in, const int* in_sizes, int n_in,
                              void* d_out, int out_size, void* d_ws, size_t ws_size,
                              hipStream_t stream) {
    const float* x      = (const float*)d_in[0];
    const int*   coords = (const int*)  d_in[1];
    const int*   cinv   = (const int*)  d_in[2];
    const float* W_red  = (const float*)d_in[3];
    const float* b_red  = (const float*)d_in[4];
    const float* W_pool = (const float*)d_in[5];
    const float* b_pool = (const float*)d_in[6];
    const float* W_att  = (const float*)d_in[7];
    const float* b_att  = (const float*)d_in[8];
    const float* W_z    = (const float*)d_in[9];
    const float* W_out  = (const float*)d_in[10];
    const float* W_l1   = (const float*)d_in[11];
    const float* W_l2   = (const float*)d_in[12];
    const float* b_l2   = (const float*)d_in[13];
    float* out = (float*)d_out;
    int n = in_sizes[0] / 64;

    char* wsb = (char*)d_ws;
    unsigned int*   red32   = (unsigned int*)(wsb);
    unsigned short* red     = (unsigned short*)(wsb);
    unsigned int*   sums_pk = (unsigned int*)(wsb + SUMS_OFF);
    float*          cnt     = (float*)(wsb + CNT_OFF);
    unsigned short* att     = (unsigned short*)(wsb + ATT_OFF);
    char*           wq      = wsb + WQ_OFF;
    unsigned short* sfeat   = (unsigned short*)(wsb + SUMS_OFF);  // alias: sums dead after k2

    k0_wprep<<<124, 256, 0, stream>>>(W_red, W_pool, W_z, W_att, W_out, W_l1, W_l2, wq);
    hipMemsetAsync(sums_pk, 0, (size_t)SEG1 * 128ull, stream);
    hipMemsetAsync(cnt, 0, (size_t)SEG1 * 4ull, stream);

    k1_mfma<<<(n + 63) / 64, 256, 0, stream>>>(x, coords, wq, b_red, red32, sums_pk, cnt, n);
    k_pyramid<<<PYRB12, 256, 0, stream>>>(sums_pk, cnt);
    k_pyr3<<<1024, 256, 0, stream>>>(sums_pk, cnt);
    k2_mfma<<<K2BT, 256, 0, stream>>>(sums_pk, cnt, wq, b_pool, att);
    k3a_mfma<<<(n + 63) / 64, 256, 0, stream>>>(coords, att, wq, b_att, sfeat, n);
    k3b_mfma<<<(n + 127) / 128, 256, 0, stream>>>(cinv, red, sfeat, wq, b_l2, out, n);
}